// Round 1
// baseline (1167.185 us; speedup 1.0000x reference)
//
#include <hip/hip_runtime.h>

// ---------------------------------------------------------------------------
// RecurrentGNN (DCRNN single step), N=100000, E=800000, HID=64, OUT=12
// Key simplifications (h0 == 0):
//   - only rows k<64 of each (2,2,128,64) dconv weight matter
//   - r-gate is dead; h_new = (1-z)*h_tilde
// ---------------------------------------------------------------------------

__global__ void deg_kernel(const int* __restrict__ row, const int* __restrict__ col,
                           const float* __restrict__ ew,
                           float* __restrict__ deg_out, float* __restrict__ deg_in, int E) {
    int e = blockIdx.x * blockDim.x + threadIdx.x;
    if (e < E) {
        float w = ew[e];
        atomicAdd(&deg_out[row[e]], w);
        atomicAdd(&deg_in[col[e]], w);
    }
}

// h = sigmoid(x @ W (24x64) + b), one thread per (node, channel)
__global__ void __launch_bounds__(256) lin2_kernel(
        const float* __restrict__ x, const float* __restrict__ W,
        const float* __restrict__ b, float* __restrict__ h, int N) {
    __shared__ float Ws[24 * 64];
    __shared__ float bs[64];
    for (int i = threadIdx.x; i < 24 * 64; i += 256) Ws[i] = W[i];
    if (threadIdx.x < 64) bs[threadIdx.x] = b[threadIdx.x];
    __syncthreads();
    int gid = blockIdx.x * 256 + threadIdx.x;
    int n = gid >> 6;
    int c = gid & 63;
    if (n >= N) return;
    const float* xr = x + (size_t)n * 24;
    float acc = bs[c];
#pragma unroll
    for (int k = 0; k < 24; ++k) acc += xr[k] * Ws[k * 64 + c];
    h[(size_t)n * 64 + c] = 1.0f / (1.0f + __expf(-acc));
}

// one wave (64 lanes) per edge, lane = channel; both diffusion directions
__global__ void __launch_bounds__(256) scatter_kernel(
        const int* __restrict__ row, const int* __restrict__ col,
        const float* __restrict__ deg_out, const float* __restrict__ deg_in,
        const float* __restrict__ h,
        float* __restrict__ p_o, float* __restrict__ p_i, int E) {
    int e = (int)((blockIdx.x * 256u + threadIdx.x) >> 6);
    int c = threadIdx.x & 63;
    if (e >= E) return;
    int r  = row[e];
    int cl = col[e];
    float so = 1.0f / deg_out[r];   // norm_out = 1/deg_out[row]
    float si = 1.0f / deg_in[r];    // norm_in  = 1/deg_in[row]  (indexed by row!)
    float hr = h[(size_t)r  * 64 + c];
    float hc = h[(size_t)cl * 64 + c];
    atomicAdd(&p_o[(size_t)cl * 64 + c], hr * so);  // out[col] += norm_out * h[row]
    atomicAdd(&p_i[(size_t)r  * 64 + c], hc * si);  // out[row] += norm_in  * h[col]
}

// z = sigmoid(h@A + p_o@B + p_i@C + b); wave per node, lane = out channel
__global__ void __launch_bounds__(256) kz_kernel(
        const float* __restrict__ h, const float* __restrict__ p_o,
        const float* __restrict__ p_i, const float* __restrict__ wz,
        const float* __restrict__ bz, float* __restrict__ z, int N) {
    __shared__ float A[64 * 64];
    __shared__ float B[64 * 64];
    __shared__ float C[64 * 64];
    for (int i = threadIdx.x; i < 64 * 64; i += 256) {
        int k = i >> 6, c = i & 63;
        A[i] = wz[(0 * 128 + k) * 64 + c] + wz[(2 * 128 + k) * 64 + c];  // w[0,0]+w[1,0]
        B[i] = wz[(1 * 128 + k) * 64 + c];                               // w[0,1]
        C[i] = wz[(3 * 128 + k) * 64 + c];                               // w[1,1]
    }
    __syncthreads();
    int wave = threadIdx.x >> 6;
    int lane = threadIdx.x & 63;
    float bias = bz[lane];
    int base = blockIdx.x * 64 + wave * 16;
    for (int t = 0; t < 16; ++t) {
        int n = base + t;
        if (n >= N) break;           // n is wave-uniform
        float hv = h[(size_t)n * 64 + lane];
        float ov = p_o[(size_t)n * 64 + lane];
        float iv = p_i[(size_t)n * 64 + lane];
        float acc = bias;
#pragma unroll
        for (int k = 0; k < 64; ++k) {
            float hk = __shfl(hv, k, 64);
            float ok = __shfl(ov, k, 64);
            float ik = __shfl(iv, k, 64);
            acc += hk * A[k * 64 + lane];
            acc += ok * B[k * 64 + lane];
            acc += ik * C[k * 64 + lane];
        }
        z[(size_t)n * 64 + lane] = 1.0f / (1.0f + __expf(-acc));
    }
}

// h_tilde = tanh(h@A + p_o@B + p_i@C + b); out = sigmoid((1-z)*h_tilde)@Wout + bout
__global__ void __launch_bounds__(256) kh_kernel(
        const float* __restrict__ h, const float* __restrict__ p_o,
        const float* __restrict__ p_i, const float* __restrict__ z,
        const float* __restrict__ wh, const float* __restrict__ bh,
        const float* __restrict__ wout, const float* __restrict__ bout,
        float* __restrict__ out, int N) {
    __shared__ float A[64 * 64];
    __shared__ float B[64 * 64];
    __shared__ float C[64 * 64];
    __shared__ float WO[64 * 12];
    for (int i = threadIdx.x; i < 64 * 64; i += 256) {
        int k = i >> 6, c = i & 63;
        A[i] = wh[(0 * 128 + k) * 64 + c] + wh[(2 * 128 + k) * 64 + c];
        B[i] = wh[(1 * 128 + k) * 64 + c];
        C[i] = wh[(3 * 128 + k) * 64 + c];
    }
    for (int i = threadIdx.x; i < 64 * 12; i += 256) WO[i] = wout[i];
    __syncthreads();
    int wave = threadIdx.x >> 6;
    int lane = threadIdx.x & 63;
    float bias = bh[lane];
    int base = blockIdx.x * 64 + wave * 16;
    for (int t = 0; t < 16; ++t) {
        int n = base + t;
        if (n >= N) break;
        float hv = h[(size_t)n * 64 + lane];
        float ov = p_o[(size_t)n * 64 + lane];
        float iv = p_i[(size_t)n * 64 + lane];
        float acc = bias;
#pragma unroll
        for (int k = 0; k < 64; ++k) {
            float hk = __shfl(hv, k, 64);
            float ok = __shfl(ov, k, 64);
            float ik = __shfl(iv, k, 64);
            acc += hk * A[k * 64 + lane];
            acc += ok * B[k * 64 + lane];
            acc += ik * C[k * 64 + lane];
        }
        float ht = tanhf(acc);
        float zv = z[(size_t)n * 64 + lane];
        float hn = (1.0f - zv) * ht;
        float s  = 1.0f / (1.0f + __expf(-hn));
        // out[n][j] = sum_c s_c * WO[c][j] + bout[j]
#pragma unroll
        for (int j = 0; j < 12; ++j) {
            float v = s * WO[lane * 12 + j];
#pragma unroll
            for (int off = 32; off > 0; off >>= 1) v += __shfl_xor(v, off, 64);
            if (lane == 0) out[(size_t)n * 12 + j] = v + bout[j];
        }
    }
}

extern "C" void kernel_launch(void* const* d_in, const int* in_sizes, int n_in,
                              void* d_out, int out_size, void* d_ws, size_t ws_size,
                              hipStream_t stream) {
    const float* x      = (const float*)d_in[0];
    const int*   ei     = (const int*)  d_in[1];
    const float* ew     = (const float*)d_in[2];
    const float* w_lin2 = (const float*)d_in[3];
    const float* b_lin2 = (const float*)d_in[4];
    const float* w_z    = (const float*)d_in[5];
    const float* b_z    = (const float*)d_in[6];
    // d_in[7], d_in[8]: w_r, b_r — dead (h0 == 0)
    const float* w_h    = (const float*)d_in[9];
    const float* b_h    = (const float*)d_in[10];
    const float* w_out  = (const float*)d_in[11];
    const float* b_out  = (const float*)d_in[12];

    int N = in_sizes[0] / 24;
    int E = in_sizes[1] / 2;
    const int* row = ei;
    const int* col = ei + E;

    float* ws  = (float*)d_ws;
    float* h   = ws;                         // N*64
    float* p_o = h   + (size_t)N * 64;       // N*64
    float* p_i = p_o + (size_t)N * 64;       // N*64
    float* z   = p_i + (size_t)N * 64;       // N*64
    float* dgo = z   + (size_t)N * 64;       // N
    float* dgi = dgo + N;                    // N

    // zero the atomic targets every call (graph replays don't re-poison)
    hipMemsetAsync(p_o, 0, (size_t)N * 64 * 2 * sizeof(float), stream);
    hipMemsetAsync(dgo, 0, (size_t)N * 2 * sizeof(float), stream);

    deg_kernel<<<(E + 255) / 256, 256, 0, stream>>>(row, col, ew, dgo, dgi, E);
    lin2_kernel<<<(N * 64 + 255) / 256, 256, 0, stream>>>(x, w_lin2, b_lin2, h, N);
    scatter_kernel<<<(int)(((size_t)E * 64 + 255) / 256), 256, 0, stream>>>(
        row, col, dgo, dgi, h, p_o, p_i, E);
    kz_kernel<<<(N + 63) / 64, 256, 0, stream>>>(h, p_o, p_i, w_z, b_z, z, N);
    kh_kernel<<<(N + 63) / 64, 256, 0, stream>>>(h, p_o, p_i, z, w_h, b_h,
                                                 w_out, b_out, (float*)d_out, N);
}

// Round 2
// 544.196 us; speedup vs baseline: 2.1448x; 2.1448x over previous
//
#include <hip/hip_runtime.h>

// ---------------------------------------------------------------------------
// RecurrentGNN (DCRNN single step), N=100000, E=800000, HID=64, OUT=12
// h0 == 0  =>  only k<64 rows of dconv weights matter; r-gate dead;
//              h_new = (1-z)*h_tilde.
// Round 1: fuse kz+kh into one tiled fp32 GEMM  [N x 192] @ [192 x 128]
//          with in-register GRU combine + fused 64->12 output projection.
// ---------------------------------------------------------------------------

__device__ __forceinline__ float sigmoid_f(float x) {
    return 1.0f / (1.0f + __expf(-x));
}
__device__ __forceinline__ float tanh_f(float x) {
    float ax = fabsf(x);
    float e = __expf(-2.0f * ax);
    float t = (1.0f - e) / (1.0f + e);
    return copysignf(t, x);
}

__global__ void deg_kernel(const int* __restrict__ row, const int* __restrict__ col,
                           const float* __restrict__ ew,
                           float* __restrict__ deg_out, float* __restrict__ deg_in, int E) {
    int e = blockIdx.x * blockDim.x + threadIdx.x;
    if (e < E) {
        float w = ew[e];
        atomicAdd(&deg_out[row[e]], w);
        atomicAdd(&deg_in[col[e]], w);
    }
}

// h = sigmoid(x @ W (24x64) + b), one thread per (node, channel)
__global__ void __launch_bounds__(256) lin2_kernel(
        const float* __restrict__ x, const float* __restrict__ W,
        const float* __restrict__ b, float* __restrict__ h, int N) {
    __shared__ float Ws[24 * 64];
    __shared__ float bs[64];
    for (int i = threadIdx.x; i < 24 * 64; i += 256) Ws[i] = W[i];
    if (threadIdx.x < 64) bs[threadIdx.x] = b[threadIdx.x];
    __syncthreads();
    int gid = blockIdx.x * 256 + threadIdx.x;
    int n = gid >> 6;
    int c = gid & 63;
    if (n >= N) return;
    const float* xr = x + (size_t)n * 24;
    float acc = bs[c];
#pragma unroll
    for (int k = 0; k < 24; ++k) acc += xr[k] * Ws[k * 64 + c];
    h[(size_t)n * 64 + c] = sigmoid_f(acc);
}

// one wave (64 lanes) per edge, lane = channel; both diffusion directions
__global__ void __launch_bounds__(256) scatter_kernel(
        const int* __restrict__ row, const int* __restrict__ col,
        const float* __restrict__ deg_out, const float* __restrict__ deg_in,
        const float* __restrict__ h,
        float* __restrict__ p_o, float* __restrict__ p_i, int E) {
    int e = (int)((blockIdx.x * 256u + threadIdx.x) >> 6);
    int c = threadIdx.x & 63;
    if (e >= E) return;
    int r  = row[e];
    int cl = col[e];
    float so = 1.0f / deg_out[r];   // norm_out = 1/deg_out[row]
    float si = 1.0f / deg_in[r];    // norm_in  = 1/deg_in[row]  (indexed by row!)
    float hr = h[(size_t)r  * 64 + c];
    float hc = h[(size_t)cl * 64 + c];
    atomicAdd(&p_o[(size_t)cl * 64 + c], hr * so);  // out[col] += norm_out * h[row]
    atomicAdd(&p_i[(size_t)r  * 64 + c], hc * si);  // out[row] += norm_in  * h[col]
}

// Build combined weights: Wc[192][128] = [A;B;C] x [z-gate | h-gate], bc[128]
__global__ void prep_kernel(const float* __restrict__ wz, const float* __restrict__ bz,
                            const float* __restrict__ wh, const float* __restrict__ bh,
                            float* __restrict__ Wc, float* __restrict__ bc) {
    int i = blockIdx.x * 256 + threadIdx.x;
    if (i < 128) bc[i] = (i < 64) ? bz[i] : bh[i - 64];
    if (i >= 192 * 128) return;
    int k = i >> 7;        // 0..191
    int c = i & 127;       // 0..127
    const float* w = (c < 64) ? wz : wh;
    int cc = c & 63;
    float v;
    if (k < 64)        v = w[(0 * 128 + k) * 64 + cc] + w[(2 * 128 + k) * 64 + cc];
    else if (k < 128)  v = w[(1 * 128 + (k - 64)) * 64 + cc];
    else               v = w[(3 * 128 + (k - 128)) * 64 + cc];
    Wc[i] = v;
}

// Fused gate GEMM + GRU combine + output projection.
// Block: 64 nodes. Threads 256: ng=t>>4 (4 nodes each), cg=t&15
// (cols cg*4..+4 of z-gate AND cols 64+cg*4..+4 of h-gate: same channels).
__global__ void __launch_bounds__(256) gates_kernel(
        const float* __restrict__ h, const float* __restrict__ p_o,
        const float* __restrict__ p_i, const float* __restrict__ Wc,
        const float* __restrict__ bc, const float* __restrict__ wout,
        const float* __restrict__ bout, float* __restrict__ out, int N) {
    __shared__ float sW[64 * 128];   // K-chunk of weights; reused as s-tile later
    __shared__ float sIn[64 * 68];   // transposed input chunk [kk][node], pad 68
    __shared__ float sWO[64 * 12];

    const int t  = threadIdx.x;
    const int ng = t >> 4;           // 0..15: nodes ng*4..+4
    const int cg = t & 15;           // 0..15: channels cg*4..+4
    const int n0 = blockIdx.x * 64;

    float acc[4][8];
#pragma unroll
    for (int j = 0; j < 4; ++j) {
        float bz_ = bc[cg * 4 + j];
        float bh_ = bc[64 + cg * 4 + j];
#pragma unroll
        for (int i = 0; i < 4; ++i) { acc[i][j] = bz_; acc[i][4 + j] = bh_; }
    }
    for (int i = t; i < 64 * 12; i += 256) sWO[i] = wout[i];

    for (int kc = 0; kc < 3; ++kc) {
        const float* src = (kc == 0) ? h : ((kc == 1) ? p_o : p_i);
        __syncthreads();
        // stage inputs transposed: sIn[kk][node]
#pragma unroll
        for (int r = 0; r < 4; ++r) {
            int idx  = r * 256 + t;      // float4 index: 16 per node row
            int node = idx >> 4;
            int k4   = idx & 15;
            int nd   = min(n0 + node, N - 1);
            const float4 v = *(const float4*)(src + (size_t)nd * 64 + k4 * 4);
            sIn[(k4 * 4 + 0) * 68 + node] = v.x;
            sIn[(k4 * 4 + 1) * 68 + node] = v.y;
            sIn[(k4 * 4 + 2) * 68 + node] = v.z;
            sIn[(k4 * 4 + 3) * 68 + node] = v.w;
        }
        // stage weight chunk: sW[kk][c], 64x128
#pragma unroll
        for (int r = 0; r < 8; ++r) {
            int idx = r * 256 + t;       // float4 index: 32 per row
            int kk  = idx >> 5;
            int c4  = idx & 31;
            *(float4*)(sW + kk * 128 + c4 * 4) =
                *(const float4*)(Wc + (size_t)(kc * 64 + kk) * 128 + c4 * 4);
        }
        __syncthreads();
#pragma unroll 8
        for (int kk = 0; kk < 64; ++kk) {
            float4 a  = *(const float4*)(sIn + kk * 68 + ng * 4);
            float4 w0 = *(const float4*)(sW + kk * 128 + cg * 4);        // z cols
            float4 w1 = *(const float4*)(sW + kk * 128 + 64 + cg * 4);   // h cols
            float av[4] = {a.x, a.y, a.z, a.w};
            float wz_[4] = {w0.x, w0.y, w0.z, w0.w};
            float wh_[4] = {w1.x, w1.y, w1.z, w1.w};
#pragma unroll
            for (int i = 0; i < 4; ++i) {
#pragma unroll
                for (int j = 0; j < 4; ++j) {
                    acc[i][j]     = fmaf(av[i], wz_[j], acc[i][j]);
                    acc[i][4 + j] = fmaf(av[i], wh_[j], acc[i][4 + j]);
                }
            }
        }
    }

    // GRU combine in-register, s-tile to LDS (reusing sW space)
    __syncthreads();
    float* sS = sW;                  // [64][68]
#pragma unroll
    for (int i = 0; i < 4; ++i) {
        int node = ng * 4 + i;
        float4 sv;
        float* svp = (float*)&sv;
#pragma unroll
        for (int j = 0; j < 4; ++j) {
            float zv = sigmoid_f(acc[i][j]);
            float ht = tanh_f(acc[i][4 + j]);
            svp[j] = sigmoid_f((1.0f - zv) * ht);
        }
        *(float4*)(sS + node * 68 + cg * 4) = sv;
    }
    __syncthreads();

    // out[node][j] = s[node] . WO[:,j] + bout[j];  64*12 = 768 = 3*256 outputs
#pragma unroll
    for (int r = 0; r < 3; ++r) {
        int o    = r * 256 + t;
        int node = o / 12;
        int j    = o % 12;
        int n    = n0 + node;
        if (n >= N) continue;
        float a = bout[j];
#pragma unroll 8
        for (int c = 0; c < 64; ++c) a = fmaf(sS[node * 68 + c], sWO[c * 12 + j], a);
        out[(size_t)n * 12 + j] = a;
    }
}

extern "C" void kernel_launch(void* const* d_in, const int* in_sizes, int n_in,
                              void* d_out, int out_size, void* d_ws, size_t ws_size,
                              hipStream_t stream) {
    const float* x      = (const float*)d_in[0];
    const int*   ei     = (const int*)  d_in[1];
    const float* ew     = (const float*)d_in[2];
    const float* w_lin2 = (const float*)d_in[3];
    const float* b_lin2 = (const float*)d_in[4];
    const float* w_z    = (const float*)d_in[5];
    const float* b_z    = (const float*)d_in[6];
    // d_in[7], d_in[8]: w_r, b_r — dead (h0 == 0)
    const float* w_h    = (const float*)d_in[9];
    const float* b_h    = (const float*)d_in[10];
    const float* w_out  = (const float*)d_in[11];
    const float* b_out  = (const float*)d_in[12];

    int N = in_sizes[0] / 24;
    int E = in_sizes[1] / 2;
    const int* row = ei;
    const int* col = ei + E;

    float* ws  = (float*)d_ws;
    float* h   = ws;                         // N*64
    float* p_o = h   + (size_t)N * 64;       // N*64
    float* p_i = p_o + (size_t)N * 64;       // N*64
    float* dgo = p_i + (size_t)N * 64;       // N
    float* dgi = dgo + N;                    // N
    float* Wc  = dgi + N;                    // 192*128
    float* bc  = Wc  + 192 * 128;            // 128

    // zero the atomic targets every call (graph replays don't re-poison)
    hipMemsetAsync(p_o, 0, (size_t)N * 64 * 2 * sizeof(float), stream);
    hipMemsetAsync(dgo, 0, (size_t)N * 2 * sizeof(float), stream);

    prep_kernel<<<(192 * 128 + 255) / 256, 256, 0, stream>>>(w_z, b_z, w_h, b_h, Wc, bc);
    deg_kernel<<<(E + 255) / 256, 256, 0, stream>>>(row, col, ew, dgo, dgi, E);
    lin2_kernel<<<(N * 64 + 255) / 256, 256, 0, stream>>>(x, w_lin2, b_lin2, h, N);
    scatter_kernel<<<(int)(((size_t)E * 64 + 255) / 256), 256, 0, stream>>>(
        row, col, dgo, dgi, h, p_o, p_i, E);
    gates_kernel<<<(N + 63) / 64, 256, 0, stream>>>(h, p_o, p_i, Wc, bc,
                                                    w_out, b_out, (float*)d_out, N);
}

// Round 3
// 528.484 us; speedup vs baseline: 2.2086x; 1.0297x over previous
//
#include <hip/hip_runtime.h>

// ---------------------------------------------------------------------------
// RecurrentGNN (DCRNN single step), N=100000, E=800000, HID=64, OUT=12
// h0 == 0  =>  only k<64 rows of dconv weights matter; r-gate dead;
//              h_new = (1-z)*h_tilde.
// Round 1: fused gate GEMM (kz+kh+out-projection in one kernel).
// Round 2: replace fp32 atomic scatter (400 MB device-scope atomic RMW) with
//          on-device CSR build + wave-per-node gather:
//            p_o[n] = sum_{col[e]=n} h[row[e]] / deg_out[row[e]]
//            p_i[n] = (1/deg_in[n]) * sum_{row[e]=n} h[col[e]]   (scale factors out)
// ---------------------------------------------------------------------------

__device__ __forceinline__ float sigmoid_f(float x) {
    return 1.0f / (1.0f + __expf(-x));
}
__device__ __forceinline__ float tanh_f(float x) {
    float ax = fabsf(x);
    float e = __expf(-2.0f * ax);
    float t = (1.0f - e) / (1.0f + e);
    return copysignf(t, x);
}

// weighted degrees + CSR histograms, one pass over edges
__global__ void __launch_bounds__(256) deg_hist_kernel(
        const int* __restrict__ row, const int* __restrict__ col,
        const float* __restrict__ ew,
        float* __restrict__ dgo, float* __restrict__ dgi,
        int* __restrict__ cnt_out, int* __restrict__ cnt_in, int E) {
    int e = blockIdx.x * 256 + threadIdx.x;
    if (e < E) {
        float w = ew[e];
        int r = row[e], c = col[e];
        atomicAdd(&dgo[r], w);
        atomicAdd(&dgi[c], w);
        atomicAdd(&cnt_out[r], 1);
        atomicAdd(&cnt_in[c], 1);
    }
}

// block-level exclusive scan of counts (y: 0=in, 1=out)
__global__ void __launch_bounds__(256) scan1_kernel(
        const int* __restrict__ ci, int* __restrict__ oi, int* __restrict__ bi,
        const int* __restrict__ co, int* __restrict__ oo, int* __restrict__ bo, int N) {
    const int* cnt = blockIdx.y ? co : ci;
    int* off = blockIdx.y ? oo : oi;
    int* bs  = blockIdx.y ? bo : bi;
    __shared__ int s[256];
    int t = threadIdx.x;
    int i = blockIdx.x * 256 + t;
    int v = (i < N) ? cnt[i] : 0;
    s[t] = v;
    __syncthreads();
    for (int d = 1; d < 256; d <<= 1) {
        int u = (t >= d) ? s[t - d] : 0;
        __syncthreads();
        s[t] += u;
        __syncthreads();
    }
    if (i < N) off[i] = s[t] - v;
    if (t == 255) bs[blockIdx.x] = s[255];
}

// scan of block sums (G <= 512), writes exclusive block offsets + total to off[N]
__global__ void __launch_bounds__(512) scan2_kernel(
        int* __restrict__ bi, int* __restrict__ oi,
        int* __restrict__ bo, int* __restrict__ oo, int G, int N) {
    int* bs  = blockIdx.y ? bo : bi;
    int* off = blockIdx.y ? oo : oi;
    __shared__ int s[512];
    int t = threadIdx.x;
    int v = (t < G) ? bs[t] : 0;
    s[t] = v;
    __syncthreads();
    for (int d = 1; d < 512; d <<= 1) {
        int u = (t >= d) ? s[t - d] : 0;
        __syncthreads();
        s[t] += u;
        __syncthreads();
    }
    if (t < G) bs[t] = s[t] - v;
    if (t == 511) off[N] = s[511];
}

// finalize offsets, init fill cursors, reciprocal degrees
__global__ void __launch_bounds__(256) scan3_kernel(
        int* __restrict__ oi, const int* __restrict__ bi, int* __restrict__ curi,
        int* __restrict__ oo, const int* __restrict__ bo, int* __restrict__ curo,
        const float* __restrict__ dgo, float* __restrict__ rdo,
        const float* __restrict__ dgi, float* __restrict__ rdi, int N) {
    int i = blockIdx.x * 256 + threadIdx.x;
    if (i >= N) return;
    if (blockIdx.y == 0) {
        int v = oi[i] + bi[i >> 8];
        oi[i] = v; curi[i] = v;
        rdo[i] = 1.0f / dgo[i];
    } else {
        int v = oo[i] + bo[i >> 8];
        oo[i] = v; curo[i] = v;
        rdi[i] = 1.0f / dgi[i];
    }
}

// scatter edge endpoints into CSR slots
__global__ void __launch_bounds__(256) fill_kernel(
        const int* __restrict__ row, const int* __restrict__ col,
        int* __restrict__ cur_in, int* __restrict__ cur_out,
        int* __restrict__ lst_in, int* __restrict__ lst_out, int E) {
    int e = blockIdx.x * 256 + threadIdx.x;
    if (e < E) {
        int r = row[e], c = col[e];
        int p = atomicAdd(&cur_in[c], 1);
        lst_in[p] = r;
        int q = atomicAdd(&cur_out[r], 1);
        lst_out[q] = c;
    }
}

// wave per node, lane = channel; both diffusion directions, no atomics
__global__ void __launch_bounds__(256) gather_kernel(
        const float* __restrict__ h,
        const int* __restrict__ off_in, const int* __restrict__ lst_in,
        const float* __restrict__ rdo,
        const int* __restrict__ off_out, const int* __restrict__ lst_out,
        const float* __restrict__ rdi,
        float* __restrict__ p_o, float* __restrict__ p_i, int N) {
    int n = blockIdx.x * 4 + (threadIdx.x >> 6);
    if (n >= N) return;
    int lane = threadIdx.x & 63;

    float acc = 0.0f;
    int s0 = off_in[n], s1 = off_in[n + 1];
    if (s0 < s1) {
        int src = lst_in[s0];
        for (int s = s0; s < s1; ++s) {
            int nxt = (s + 1 < s1) ? lst_in[s + 1] : 0;   // prefetch next index
            acc = fmaf(h[(size_t)src * 64 + lane], rdo[src], acc);
            src = nxt;
        }
    }
    p_o[(size_t)n * 64 + lane] = acc;

    float acc2 = 0.0f;
    s0 = off_out[n]; s1 = off_out[n + 1];
    if (s0 < s1) {
        int src = lst_out[s0];
        for (int s = s0; s < s1; ++s) {
            int nxt = (s + 1 < s1) ? lst_out[s + 1] : 0;
            acc2 += h[(size_t)src * 64 + lane];
            src = nxt;
        }
    }
    p_i[(size_t)n * 64 + lane] = acc2 * rdi[n];
}

// h = sigmoid(x @ W (24x64) + b), one thread per (node, channel)
__global__ void __launch_bounds__(256) lin2_kernel(
        const float* __restrict__ x, const float* __restrict__ W,
        const float* __restrict__ b, float* __restrict__ h, int N) {
    __shared__ float Ws[24 * 64];
    __shared__ float bs[64];
    for (int i = threadIdx.x; i < 24 * 64; i += 256) Ws[i] = W[i];
    if (threadIdx.x < 64) bs[threadIdx.x] = b[threadIdx.x];
    __syncthreads();
    int gid = blockIdx.x * 256 + threadIdx.x;
    int n = gid >> 6;
    int c = gid & 63;
    if (n >= N) return;
    const float* xr = x + (size_t)n * 24;
    float acc = bs[c];
#pragma unroll
    for (int k = 0; k < 24; ++k) acc += xr[k] * Ws[k * 64 + c];
    h[(size_t)n * 64 + c] = sigmoid_f(acc);
}

// Build combined weights: Wc[192][128] = [A;B;C] x [z-gate | h-gate], bc[128]
__global__ void prep_kernel(const float* __restrict__ wz, const float* __restrict__ bz,
                            const float* __restrict__ wh, const float* __restrict__ bh,
                            float* __restrict__ Wc, float* __restrict__ bc) {
    int i = blockIdx.x * 256 + threadIdx.x;
    if (i < 128) bc[i] = (i < 64) ? bz[i] : bh[i - 64];
    if (i >= 192 * 128) return;
    int k = i >> 7;        // 0..191
    int c = i & 127;       // 0..127
    const float* w = (c < 64) ? wz : wh;
    int cc = c & 63;
    float v;
    if (k < 64)        v = w[(0 * 128 + k) * 64 + cc] + w[(2 * 128 + k) * 64 + cc];
    else if (k < 128)  v = w[(1 * 128 + (k - 64)) * 64 + cc];
    else               v = w[(3 * 128 + (k - 128)) * 64 + cc];
    Wc[i] = v;
}

// Fused gate GEMM + GRU combine + output projection.
__global__ void __launch_bounds__(256) gates_kernel(
        const float* __restrict__ h, const float* __restrict__ p_o,
        const float* __restrict__ p_i, const float* __restrict__ Wc,
        const float* __restrict__ bc, const float* __restrict__ wout,
        const float* __restrict__ bout, float* __restrict__ out, int N) {
    __shared__ float sW[64 * 128];   // K-chunk of weights; reused as s-tile later
    __shared__ float sIn[64 * 68];   // transposed input chunk [kk][node], pad 68
    __shared__ float sWO[64 * 12];

    const int t  = threadIdx.x;
    const int ng = t >> 4;           // 0..15: nodes ng*4..+4
    const int cg = t & 15;           // 0..15: channels cg*4..+4
    const int n0 = blockIdx.x * 64;

    float acc[4][8];
#pragma unroll
    for (int j = 0; j < 4; ++j) {
        float bz_ = bc[cg * 4 + j];
        float bh_ = bc[64 + cg * 4 + j];
#pragma unroll
        for (int i = 0; i < 4; ++i) { acc[i][j] = bz_; acc[i][4 + j] = bh_; }
    }
    for (int i = t; i < 64 * 12; i += 256) sWO[i] = wout[i];

    for (int kc = 0; kc < 3; ++kc) {
        const float* src = (kc == 0) ? h : ((kc == 1) ? p_o : p_i);
        __syncthreads();
        // stage inputs transposed: sIn[kk][node]
#pragma unroll
        for (int r = 0; r < 4; ++r) {
            int idx  = r * 256 + t;      // float4 index: 16 per node row
            int node = idx >> 4;
            int k4   = idx & 15;
            int nd   = min(n0 + node, N - 1);
            const float4 v = *(const float4*)(src + (size_t)nd * 64 + k4 * 4);
            sIn[(k4 * 4 + 0) * 68 + node] = v.x;
            sIn[(k4 * 4 + 1) * 68 + node] = v.y;
            sIn[(k4 * 4 + 2) * 68 + node] = v.z;
            sIn[(k4 * 4 + 3) * 68 + node] = v.w;
        }
        // stage weight chunk: sW[kk][c], 64x128
#pragma unroll
        for (int r = 0; r < 8; ++r) {
            int idx = r * 256 + t;       // float4 index: 32 per row
            int kk  = idx >> 5;
            int c4  = idx & 31;
            *(float4*)(sW + kk * 128 + c4 * 4) =
                *(const float4*)(Wc + (size_t)(kc * 64 + kk) * 128 + c4 * 4);
        }
        __syncthreads();
#pragma unroll 8
        for (int kk = 0; kk < 64; ++kk) {
            float4 a  = *(const float4*)(sIn + kk * 68 + ng * 4);
            float4 w0 = *(const float4*)(sW + kk * 128 + cg * 4);        // z cols
            float4 w1 = *(const float4*)(sW + kk * 128 + 64 + cg * 4);   // h cols
            float av[4] = {a.x, a.y, a.z, a.w};
            float wz_[4] = {w0.x, w0.y, w0.z, w0.w};
            float wh_[4] = {w1.x, w1.y, w1.z, w1.w};
#pragma unroll
            for (int i = 0; i < 4; ++i) {
#pragma unroll
                for (int j = 0; j < 4; ++j) {
                    acc[i][j]     = fmaf(av[i], wz_[j], acc[i][j]);
                    acc[i][4 + j] = fmaf(av[i], wh_[j], acc[i][4 + j]);
                }
            }
        }
    }

    // GRU combine in-register, s-tile to LDS (reusing sW space)
    __syncthreads();
    float* sS = sW;                  // [64][68]
#pragma unroll
    for (int i = 0; i < 4; ++i) {
        int node = ng * 4 + i;
        float4 sv;
        float* svp = (float*)&sv;
#pragma unroll
        for (int j = 0; j < 4; ++j) {
            float zv = sigmoid_f(acc[i][j]);
            float ht = tanh_f(acc[i][4 + j]);
            svp[j] = sigmoid_f((1.0f - zv) * ht);
        }
        *(float4*)(sS + node * 68 + cg * 4) = sv;
    }
    __syncthreads();

    // out[node][j] = s[node] . WO[:,j] + bout[j];  64*12 = 768 = 3*256 outputs
#pragma unroll
    for (int r = 0; r < 3; ++r) {
        int o    = r * 256 + t;
        int node = o / 12;
        int j    = o % 12;
        int n    = n0 + node;
        if (n >= N) continue;
        float a = bout[j];
#pragma unroll 8
        for (int c = 0; c < 64; ++c) a = fmaf(sS[node * 68 + c], sWO[c * 12 + j], a);
        out[(size_t)n * 12 + j] = a;
    }
}

extern "C" void kernel_launch(void* const* d_in, const int* in_sizes, int n_in,
                              void* d_out, int out_size, void* d_ws, size_t ws_size,
                              hipStream_t stream) {
    const float* x      = (const float*)d_in[0];
    const int*   ei     = (const int*)  d_in[1];
    const float* ew     = (const float*)d_in[2];
    const float* w_lin2 = (const float*)d_in[3];
    const float* b_lin2 = (const float*)d_in[4];
    const float* w_z    = (const float*)d_in[5];
    const float* b_z    = (const float*)d_in[6];
    // d_in[7], d_in[8]: w_r, b_r — dead (h0 == 0)
    const float* w_h    = (const float*)d_in[9];
    const float* b_h    = (const float*)d_in[10];
    const float* w_out  = (const float*)d_in[11];
    const float* b_out  = (const float*)d_in[12];

    int N = in_sizes[0] / 24;
    int E = in_sizes[1] / 2;
    const int* row = ei;
    const int* col = ei + E;
    int G = (N + 255) / 256;   // <= 512 required by scan2 (N <= 131072)

    float* ws   = (float*)d_ws;
    float* h    = ws;                          // N*64
    float* p_o  = h   + (size_t)N * 64;        // N*64
    float* p_i  = p_o + (size_t)N * 64;        // N*64
    float* Wc   = p_i + (size_t)N * 64;        // 192*128
    float* bc   = Wc  + 192 * 128;             // 128
    float* dgo  = bc  + 128;                   // N  (zeroed)
    float* dgi  = dgo + N;                     // N  (zeroed)
    int* cnt_in  = (int*)(dgi + N);            // N  (zeroed)
    int* cnt_out = cnt_in + N;                 // N  (zeroed)
    float* rdo  = (float*)(cnt_out + N);       // N
    float* rdi  = rdo + N;                     // N
    int* off_in  = (int*)(rdi + N);            // N+1
    int* off_out = off_in + N + 1;             // N+1
    int* cur_in  = off_out + N + 1;            // N
    int* cur_out = cur_in + N;                 // N
    int* lst_in  = cur_out + N;                // E
    int* lst_out = lst_in + E;                 // E
    int* bsum_in  = lst_out + E;               // 512
    int* bsum_out = bsum_in + 512;             // 512

    // zero dgo,dgi,cnt_in,cnt_out (contiguous, 16N bytes)
    hipMemsetAsync(dgo, 0, (size_t)N * 4 * sizeof(float), stream);

    prep_kernel<<<(192 * 128 + 255) / 256, 256, 0, stream>>>(w_z, b_z, w_h, b_h, Wc, bc);
    deg_hist_kernel<<<(E + 255) / 256, 256, 0, stream>>>(row, col, ew, dgo, dgi,
                                                         cnt_out, cnt_in, E);
    scan1_kernel<<<dim3(G, 2), 256, 0, stream>>>(cnt_in, off_in, bsum_in,
                                                 cnt_out, off_out, bsum_out, N);
    scan2_kernel<<<dim3(1, 2), 512, 0, stream>>>(bsum_in, off_in, bsum_out, off_out, G, N);
    scan3_kernel<<<dim3(G, 2), 256, 0, stream>>>(off_in, bsum_in, cur_in,
                                                 off_out, bsum_out, cur_out,
                                                 dgo, rdo, dgi, rdi, N);
    lin2_kernel<<<(N * 64 + 255) / 256, 256, 0, stream>>>(x, w_lin2, b_lin2, h, N);
    fill_kernel<<<(E + 255) / 256, 256, 0, stream>>>(row, col, cur_in, cur_out,
                                                     lst_in, lst_out, E);
    gather_kernel<<<(N + 3) / 4, 256, 0, stream>>>(h, off_in, lst_in, rdo,
                                                   off_out, lst_out, rdi, p_o, p_i, N);
    gates_kernel<<<(N + 63) / 64, 256, 0, stream>>>(h, p_o, p_i, Wc, bc,
                                                    w_out, b_out, (float*)d_out, N);
}

// Round 4
// 455.394 us; speedup vs baseline: 2.5630x; 1.1605x over previous
//
#include <hip/hip_runtime.h>

// ---------------------------------------------------------------------------
// RecurrentGNN (DCRNN single step), N=100000, E=800000, HID=64, OUT=12
// h0 == 0  =>  only k<64 rows of dconv weights matter; r-gate dead;
//              h_new = (1-z)*h_tilde.
// Round 1: fused gate GEMM (kz+kh+out-projection in one kernel).
// Round 2: CSR build + wave-per-node gather (no fp32 atomics).
// Round 3: MLP-unrolled gather (8-edge chunks of independent loads) and
//          direction-parallel blocks (blockIdx.y) — gather was latency-bound
//          (VALUBusy 21%, HBM 20%).
// ---------------------------------------------------------------------------

__device__ __forceinline__ float sigmoid_f(float x) {
    return 1.0f / (1.0f + __expf(-x));
}
__device__ __forceinline__ float tanh_f(float x) {
    float ax = fabsf(x);
    float e = __expf(-2.0f * ax);
    float t = (1.0f - e) / (1.0f + e);
    return copysignf(t, x);
}

// weighted degrees + CSR histograms, one pass over edges
__global__ void __launch_bounds__(256) deg_hist_kernel(
        const int* __restrict__ row, const int* __restrict__ col,
        const float* __restrict__ ew,
        float* __restrict__ dgo, float* __restrict__ dgi,
        int* __restrict__ cnt_out, int* __restrict__ cnt_in, int E) {
    int e = blockIdx.x * 256 + threadIdx.x;
    if (e < E) {
        float w = ew[e];
        int r = row[e], c = col[e];
        atomicAdd(&dgo[r], w);
        atomicAdd(&dgi[c], w);
        atomicAdd(&cnt_out[r], 1);
        atomicAdd(&cnt_in[c], 1);
    }
}

// block-level exclusive scan of counts (y: 0=in, 1=out)
__global__ void __launch_bounds__(256) scan1_kernel(
        const int* __restrict__ ci, int* __restrict__ oi, int* __restrict__ bi,
        const int* __restrict__ co, int* __restrict__ oo, int* __restrict__ bo, int N) {
    const int* cnt = blockIdx.y ? co : ci;
    int* off = blockIdx.y ? oo : oi;
    int* bs  = blockIdx.y ? bo : bi;
    __shared__ int s[256];
    int t = threadIdx.x;
    int i = blockIdx.x * 256 + t;
    int v = (i < N) ? cnt[i] : 0;
    s[t] = v;
    __syncthreads();
    for (int d = 1; d < 256; d <<= 1) {
        int u = (t >= d) ? s[t - d] : 0;
        __syncthreads();
        s[t] += u;
        __syncthreads();
    }
    if (i < N) off[i] = s[t] - v;
    if (t == 255) bs[blockIdx.x] = s[255];
}

// scan of block sums (G <= 512), writes exclusive block offsets + total to off[N]
__global__ void __launch_bounds__(512) scan2_kernel(
        int* __restrict__ bi, int* __restrict__ oi,
        int* __restrict__ bo, int* __restrict__ oo, int G, int N) {
    int* bs  = blockIdx.y ? bo : bi;
    int* off = blockIdx.y ? oo : oi;
    __shared__ int s[512];
    int t = threadIdx.x;
    int v = (t < G) ? bs[t] : 0;
    s[t] = v;
    __syncthreads();
    for (int d = 1; d < 512; d <<= 1) {
        int u = (t >= d) ? s[t - d] : 0;
        __syncthreads();
        s[t] += u;
        __syncthreads();
    }
    if (t < G) bs[t] = s[t] - v;
    if (t == 511) off[N] = s[511];
}

// finalize offsets, init fill cursors, reciprocal degrees
__global__ void __launch_bounds__(256) scan3_kernel(
        int* __restrict__ oi, const int* __restrict__ bi, int* __restrict__ curi,
        int* __restrict__ oo, const int* __restrict__ bo, int* __restrict__ curo,
        const float* __restrict__ dgo, float* __restrict__ rdo,
        const float* __restrict__ dgi, float* __restrict__ rdi, int N) {
    int i = blockIdx.x * 256 + threadIdx.x;
    if (i >= N) return;
    if (blockIdx.y == 0) {
        int v = oi[i] + bi[i >> 8];
        oi[i] = v; curi[i] = v;
        rdo[i] = 1.0f / dgo[i];
    } else {
        int v = oo[i] + bo[i >> 8];
        oo[i] = v; curo[i] = v;
        rdi[i] = 1.0f / dgi[i];
    }
}

// scatter edge endpoints into CSR slots
__global__ void __launch_bounds__(256) fill_kernel(
        const int* __restrict__ row, const int* __restrict__ col,
        int* __restrict__ cur_in, int* __restrict__ cur_out,
        int* __restrict__ lst_in, int* __restrict__ lst_out, int E) {
    int e = blockIdx.x * 256 + threadIdx.x;
    if (e < E) {
        int r = row[e], c = col[e];
        int p = atomicAdd(&cur_in[c], 1);
        lst_in[p] = r;
        int q = atomicAdd(&cur_out[r], 1);
        lst_out[q] = c;
    }
}

// wave per (node, direction); lane = channel. 8-edge chunks of independent
// loads to break the index->row dependent-latency chain.
__global__ void __launch_bounds__(256) gather_kernel(
        const float* __restrict__ h,
        const int* __restrict__ off_in, const int* __restrict__ lst_in,
        const float* __restrict__ rdo,
        const int* __restrict__ off_out, const int* __restrict__ lst_out,
        const float* __restrict__ rdi,
        float* __restrict__ p_o, float* __restrict__ p_i, int N) {
    int n = blockIdx.x * 4 + (threadIdx.x >> 6);
    if (n >= N) return;
    int lane = threadIdx.x & 63;

    if (blockIdx.y == 0) {
        // p_o[n] = sum_{col[e]=n} h[row[e]] * rdo[row[e]]
        int s0 = off_in[n], s1 = off_in[n + 1];
        float acc = 0.0f;
        for (int s = s0; s < s1; s += 8) {
            int m = s1 - s;
            int idx[8];
#pragma unroll
            for (int j = 0; j < 8; ++j) idx[j] = lst_in[(s + j < s1) ? s + j : s1 - 1];
            float w[8];
#pragma unroll
            for (int j = 0; j < 8; ++j) w[j] = (j < m) ? rdo[idx[j]] : 0.0f;
            float v[8];
#pragma unroll
            for (int j = 0; j < 8; ++j) v[j] = h[(size_t)idx[j] * 64 + lane];
#pragma unroll
            for (int j = 0; j < 8; ++j) acc = fmaf(v[j], w[j], acc);
        }
        p_o[(size_t)n * 64 + lane] = acc;
    } else {
        // p_i[n] = rdi[n] * sum_{row[e]=n} h[col[e]]
        int s0 = off_out[n], s1 = off_out[n + 1];
        float acc = 0.0f;
        for (int s = s0; s < s1; s += 8) {
            int m = s1 - s;
            int idx[8];
#pragma unroll
            for (int j = 0; j < 8; ++j) idx[j] = lst_out[(s + j < s1) ? s + j : s1 - 1];
            float v[8];
#pragma unroll
            for (int j = 0; j < 8; ++j) v[j] = h[(size_t)idx[j] * 64 + lane];
#pragma unroll
            for (int j = 0; j < 8; ++j) acc += (j < m) ? v[j] : 0.0f;
        }
        p_i[(size_t)n * 64 + lane] = acc * rdi[n];
    }
}

// h = sigmoid(x @ W (24x64) + b), one thread per (node, channel)
__global__ void __launch_bounds__(256) lin2_kernel(
        const float* __restrict__ x, const float* __restrict__ W,
        const float* __restrict__ b, float* __restrict__ h, int N) {
    __shared__ float Ws[24 * 64];
    __shared__ float bs[64];
    for (int i = threadIdx.x; i < 24 * 64; i += 256) Ws[i] = W[i];
    if (threadIdx.x < 64) bs[threadIdx.x] = b[threadIdx.x];
    __syncthreads();
    int gid = blockIdx.x * 256 + threadIdx.x;
    int n = gid >> 6;
    int c = gid & 63;
    if (n >= N) return;
    const float* xr = x + (size_t)n * 24;
    float acc = bs[c];
#pragma unroll
    for (int k = 0; k < 24; ++k) acc += xr[k] * Ws[k * 64 + c];
    h[(size_t)n * 64 + c] = sigmoid_f(acc);
}

// Build combined weights: Wc[192][128] = [A;B;C] x [z-gate | h-gate], bc[128]
__global__ void prep_kernel(const float* __restrict__ wz, const float* __restrict__ bz,
                            const float* __restrict__ wh, const float* __restrict__ bh,
                            float* __restrict__ Wc, float* __restrict__ bc) {
    int i = blockIdx.x * 256 + threadIdx.x;
    if (i < 128) bc[i] = (i < 64) ? bz[i] : bh[i - 64];
    if (i >= 192 * 128) return;
    int k = i >> 7;        // 0..191
    int c = i & 127;       // 0..127
    const float* w = (c < 64) ? wz : wh;
    int cc = c & 63;
    float v;
    if (k < 64)        v = w[(0 * 128 + k) * 64 + cc] + w[(2 * 128 + k) * 64 + cc];
    else if (k < 128)  v = w[(1 * 128 + (k - 64)) * 64 + cc];
    else               v = w[(3 * 128 + (k - 128)) * 64 + cc];
    Wc[i] = v;
}

// Fused gate GEMM + GRU combine + output projection.
__global__ void __launch_bounds__(256) gates_kernel(
        const float* __restrict__ h, const float* __restrict__ p_o,
        const float* __restrict__ p_i, const float* __restrict__ Wc,
        const float* __restrict__ bc, const float* __restrict__ wout,
        const float* __restrict__ bout, float* __restrict__ out, int N) {
    __shared__ float sW[64 * 128];   // K-chunk of weights; reused as s-tile later
    __shared__ float sIn[64 * 68];   // transposed input chunk [kk][node], pad 68
    __shared__ float sWO[64 * 12];

    const int t  = threadIdx.x;
    const int ng = t >> 4;           // 0..15: nodes ng*4..+4
    const int cg = t & 15;           // 0..15: channels cg*4..+4
    const int n0 = blockIdx.x * 64;

    float acc[4][8];
#pragma unroll
    for (int j = 0; j < 4; ++j) {
        float bz_ = bc[cg * 4 + j];
        float bh_ = bc[64 + cg * 4 + j];
#pragma unroll
        for (int i = 0; i < 4; ++i) { acc[i][j] = bz_; acc[i][4 + j] = bh_; }
    }
    for (int i = t; i < 64 * 12; i += 256) sWO[i] = wout[i];

    for (int kc = 0; kc < 3; ++kc) {
        const float* src = (kc == 0) ? h : ((kc == 1) ? p_o : p_i);
        __syncthreads();
        // stage inputs transposed: sIn[kk][node]
#pragma unroll
        for (int r = 0; r < 4; ++r) {
            int idx  = r * 256 + t;      // float4 index: 16 per node row
            int node = idx >> 4;
            int k4   = idx & 15;
            int nd   = min(n0 + node, N - 1);
            const float4 v = *(const float4*)(src + (size_t)nd * 64 + k4 * 4);
            sIn[(k4 * 4 + 0) * 68 + node] = v.x;
            sIn[(k4 * 4 + 1) * 68 + node] = v.y;
            sIn[(k4 * 4 + 2) * 68 + node] = v.z;
            sIn[(k4 * 4 + 3) * 68 + node] = v.w;
        }
        // stage weight chunk: sW[kk][c], 64x128
#pragma unroll
        for (int r = 0; r < 8; ++r) {
            int idx = r * 256 + t;       // float4 index: 32 per row
            int kk  = idx >> 5;
            int c4  = idx & 31;
            *(float4*)(sW + kk * 128 + c4 * 4) =
                *(const float4*)(Wc + (size_t)(kc * 64 + kk) * 128 + c4 * 4);
        }
        __syncthreads();
#pragma unroll 8
        for (int kk = 0; kk < 64; ++kk) {
            float4 a  = *(const float4*)(sIn + kk * 68 + ng * 4);
            float4 w0 = *(const float4*)(sW + kk * 128 + cg * 4);        // z cols
            float4 w1 = *(const float4*)(sW + kk * 128 + 64 + cg * 4);   // h cols
            float av[4] = {a.x, a.y, a.z, a.w};
            float wz_[4] = {w0.x, w0.y, w0.z, w0.w};
            float wh_[4] = {w1.x, w1.y, w1.z, w1.w};
#pragma unroll
            for (int i = 0; i < 4; ++i) {
#pragma unroll
                for (int j = 0; j < 4; ++j) {
                    acc[i][j]     = fmaf(av[i], wz_[j], acc[i][j]);
                    acc[i][4 + j] = fmaf(av[i], wh_[j], acc[i][4 + j]);
                }
            }
        }
    }

    // GRU combine in-register, s-tile to LDS (reusing sW space)
    __syncthreads();
    float* sS = sW;                  // [64][68]
#pragma unroll
    for (int i = 0; i < 4; ++i) {
        int node = ng * 4 + i;
        float4 sv;
        float* svp = (float*)&sv;
#pragma unroll
        for (int j = 0; j < 4; ++j) {
            float zv = sigmoid_f(acc[i][j]);
            float ht = tanh_f(acc[i][4 + j]);
            svp[j] = sigmoid_f((1.0f - zv) * ht);
        }
        *(float4*)(sS + node * 68 + cg * 4) = sv;
    }
    __syncthreads();

    // out[node][j] = s[node] . WO[:,j] + bout[j];  64*12 = 768 = 3*256 outputs
#pragma unroll
    for (int r = 0; r < 3; ++r) {
        int o    = r * 256 + t;
        int node = o / 12;
        int j    = o % 12;
        int n    = n0 + node;
        if (n >= N) continue;
        float a = bout[j];
#pragma unroll 8
        for (int c = 0; c < 64; ++c) a = fmaf(sS[node * 68 + c], sWO[c * 12 + j], a);
        out[(size_t)n * 12 + j] = a;
    }
}

extern "C" void kernel_launch(void* const* d_in, const int* in_sizes, int n_in,
                              void* d_out, int out_size, void* d_ws, size_t ws_size,
                              hipStream_t stream) {
    const float* x      = (const float*)d_in[0];
    const int*   ei     = (const int*)  d_in[1];
    const float* ew     = (const float*)d_in[2];
    const float* w_lin2 = (const float*)d_in[3];
    const float* b_lin2 = (const float*)d_in[4];
    const float* w_z    = (const float*)d_in[5];
    const float* b_z    = (const float*)d_in[6];
    // d_in[7], d_in[8]: w_r, b_r — dead (h0 == 0)
    const float* w_h    = (const float*)d_in[9];
    const float* b_h    = (const float*)d_in[10];
    const float* w_out  = (const float*)d_in[11];
    const float* b_out  = (const float*)d_in[12];

    int N = in_sizes[0] / 24;
    int E = in_sizes[1] / 2;
    const int* row = ei;
    const int* col = ei + E;
    int G = (N + 255) / 256;   // <= 512 required by scan2 (N <= 131072)

    float* ws   = (float*)d_ws;
    float* h    = ws;                          // N*64
    float* p_o  = h   + (size_t)N * 64;        // N*64
    float* p_i  = p_o + (size_t)N * 64;        // N*64
    float* Wc   = p_i + (size_t)N * 64;        // 192*128
    float* bc   = Wc  + 192 * 128;             // 128
    float* dgo  = bc  + 128;                   // N  (zeroed)
    float* dgi  = dgo + N;                     // N  (zeroed)
    int* cnt_in  = (int*)(dgi + N);            // N  (zeroed)
    int* cnt_out = cnt_in + N;                 // N  (zeroed)
    float* rdo  = (float*)(cnt_out + N);       // N
    float* rdi  = rdo + N;                     // N
    int* off_in  = (int*)(rdi + N);            // N+1
    int* off_out = off_in + N + 1;             // N+1
    int* cur_in  = off_out + N + 1;            // N
    int* cur_out = cur_in + N;                 // N
    int* lst_in  = cur_out + N;                // E
    int* lst_out = lst_in + E;                 // E
    int* bsum_in  = lst_out + E;               // 512
    int* bsum_out = bsum_in + 512;             // 512

    // zero dgo,dgi,cnt_in,cnt_out (contiguous, 16N bytes)
    hipMemsetAsync(dgo, 0, (size_t)N * 4 * sizeof(float), stream);

    prep_kernel<<<(192 * 128 + 255) / 256, 256, 0, stream>>>(w_z, b_z, w_h, b_h, Wc, bc);
    deg_hist_kernel<<<(E + 255) / 256, 256, 0, stream>>>(row, col, ew, dgo, dgi,
                                                         cnt_out, cnt_in, E);
    scan1_kernel<<<dim3(G, 2), 256, 0, stream>>>(cnt_in, off_in, bsum_in,
                                                 cnt_out, off_out, bsum_out, N);
    scan2_kernel<<<dim3(1, 2), 512, 0, stream>>>(bsum_in, off_in, bsum_out, off_out, G, N);
    scan3_kernel<<<dim3(G, 2), 256, 0, stream>>>(off_in, bsum_in, cur_in,
                                                 off_out, bsum_out, cur_out,
                                                 dgo, rdo, dgi, rdi, N);
    lin2_kernel<<<(N * 64 + 255) / 256, 256, 0, stream>>>(x, w_lin2, b_lin2, h, N);
    fill_kernel<<<(E + 255) / 256, 256, 0, stream>>>(row, col, cur_in, cur_out,
                                                     lst_in, lst_out, E);
    gather_kernel<<<dim3((N + 3) / 4, 2), 256, 0, stream>>>(h, off_in, lst_in, rdo,
                                                            off_out, lst_out, rdi,
                                                            p_o, p_i, N);
    gates_kernel<<<(N + 63) / 64, 256, 0, stream>>>(h, p_o, p_i, Wc, bc,
                                                    w_out, b_out, (float*)d_out, N);
}

// Round 5
// 313.571 us; speedup vs baseline: 3.7222x; 1.4523x over previous
//
#include <hip/hip_runtime.h>

// ---------------------------------------------------------------------------
// RecurrentGNN (DCRNN single step), N=100000, E=800000, HID=64, OUT=12
// h0 == 0  =>  only k<64 rows of dconv weights matter; r-gate dead;
//              h_new = (1-z)*h_tilde.
// Round 1: fused gate GEMM (kz+kh+out-projection in one kernel).
// Round 2: CSR build + wave-per-node gather (no fp32 atomics).
// Round 3: MLP-unrolled gather + direction-parallel blocks.
// Round 4: packed u64 histogram atomic ((count<<48)|fix30(ew)) whose RETURN
//          value assigns each edge its CSR slot -> deg_hist does 2 atomics
//          per edge (was 4) and fill does 0 (was 2).
// ---------------------------------------------------------------------------

__device__ __forceinline__ float sigmoid_f(float x) {
    return 1.0f / (1.0f + __expf(-x));
}
__device__ __forceinline__ float tanh_f(float x) {
    float ax = fabsf(x);
    float e = __expf(-2.0f * ax);
    float t = (1.0f - e) / (1.0f + e);
    return copysignf(t, x);
}

#define FIX_SCALE 1073741824.0f            // 2^30
#define FIX_INV   9.313225746154785e-10f   // 2^-30
#define FIX_MASK  0xFFFFFFFFFFFFull        // low 48 bits

// packed degree+count histogram; returned count = CSR slot for this edge
__global__ void __launch_bounds__(256) deg_hist_kernel(
        const int* __restrict__ row, const int* __restrict__ col,
        const float* __restrict__ ew,
        unsigned long long* __restrict__ pack_out,
        unsigned long long* __restrict__ pack_in,
        int* __restrict__ slot_out, int* __restrict__ slot_in, int E) {
    int e = blockIdx.x * 256 + threadIdx.x;
    if (e < E) {
        float w = ew[e];
        int r = row[e], c = col[e];
        unsigned long long fx = (unsigned long long)(w * FIX_SCALE + 0.5f);
        unsigned long long v = (1ull << 48) | fx;
        unsigned long long a = atomicAdd(&pack_out[r], v);
        unsigned long long b = atomicAdd(&pack_in[c], v);
        slot_out[e] = (int)(a >> 48);
        slot_in[e]  = (int)(b >> 48);
    }
}

// block-level exclusive scan of counts (y: 0=in, 1=out)
__global__ void __launch_bounds__(256) scan1_kernel(
        const unsigned long long* __restrict__ pi, int* __restrict__ oi, int* __restrict__ bi,
        const unsigned long long* __restrict__ po, int* __restrict__ oo, int* __restrict__ bo,
        int N) {
    const unsigned long long* pk = blockIdx.y ? po : pi;
    int* off = blockIdx.y ? oo : oi;
    int* bs  = blockIdx.y ? bo : bi;
    __shared__ int s[256];
    int t = threadIdx.x;
    int i = blockIdx.x * 256 + t;
    int v = (i < N) ? (int)(pk[i] >> 48) : 0;
    s[t] = v;
    __syncthreads();
    for (int d = 1; d < 256; d <<= 1) {
        int u = (t >= d) ? s[t - d] : 0;
        __syncthreads();
        s[t] += u;
        __syncthreads();
    }
    if (i < N) off[i] = s[t] - v;
    if (t == 255) bs[blockIdx.x] = s[255];
}

// scan of block sums (G <= 512), writes exclusive block offsets + total to off[N]
__global__ void __launch_bounds__(512) scan2_kernel(
        int* __restrict__ bi, int* __restrict__ oi,
        int* __restrict__ bo, int* __restrict__ oo, int G, int N) {
    int* bs  = blockIdx.y ? bo : bi;
    int* off = blockIdx.y ? oo : oi;
    __shared__ int s[512];
    int t = threadIdx.x;
    int v = (t < G) ? bs[t] : 0;
    s[t] = v;
    __syncthreads();
    for (int d = 1; d < 512; d <<= 1) {
        int u = (t >= d) ? s[t - d] : 0;
        __syncthreads();
        s[t] += u;
        __syncthreads();
    }
    if (t < G) bs[t] = s[t] - v;
    if (t == 511) off[N] = s[511];
}

// finalize offsets + reciprocal degrees from packed low bits
__global__ void __launch_bounds__(256) scan3_kernel(
        int* __restrict__ oi, const int* __restrict__ bi,
        int* __restrict__ oo, const int* __restrict__ bo,
        const unsigned long long* __restrict__ pack_out,
        const unsigned long long* __restrict__ pack_in,
        float* __restrict__ rdo, float* __restrict__ rdi, int N) {
    int i = blockIdx.x * 256 + threadIdx.x;
    if (i >= N) return;
    if (blockIdx.y == 0) {
        oi[i] += bi[i >> 8];
        rdo[i] = 1.0f / ((float)(pack_out[i] & FIX_MASK) * FIX_INV);
    } else {
        oo[i] += bo[i >> 8];
        rdi[i] = 1.0f / ((float)(pack_in[i] & FIX_MASK) * FIX_INV);
    }
}

// place edge endpoints at precomputed slots — no atomics
__global__ void __launch_bounds__(256) fill_kernel(
        const int* __restrict__ row, const int* __restrict__ col,
        const int* __restrict__ off_in, const int* __restrict__ off_out,
        const int* __restrict__ slot_in, const int* __restrict__ slot_out,
        int* __restrict__ lst_in, int* __restrict__ lst_out, int E) {
    int e = blockIdx.x * 256 + threadIdx.x;
    if (e < E) {
        int r = row[e], c = col[e];
        lst_in[off_in[c] + slot_in[e]] = r;
        lst_out[off_out[r] + slot_out[e]] = c;
    }
}

// wave per (node, direction); lane = channel. 8-edge chunks of independent
// loads to break the index->row dependent-latency chain.
__global__ void __launch_bounds__(256) gather_kernel(
        const float* __restrict__ h,
        const int* __restrict__ off_in, const int* __restrict__ lst_in,
        const float* __restrict__ rdo,
        const int* __restrict__ off_out, const int* __restrict__ lst_out,
        const float* __restrict__ rdi,
        float* __restrict__ p_o, float* __restrict__ p_i, int N) {
    int n = blockIdx.x * 4 + (threadIdx.x >> 6);
    if (n >= N) return;
    int lane = threadIdx.x & 63;

    if (blockIdx.y == 0) {
        // p_o[n] = sum_{col[e]=n} h[row[e]] * rdo[row[e]]
        int s0 = off_in[n], s1 = off_in[n + 1];
        float acc = 0.0f;
        for (int s = s0; s < s1; s += 8) {
            int m = s1 - s;
            int idx[8];
#pragma unroll
            for (int j = 0; j < 8; ++j) idx[j] = lst_in[(s + j < s1) ? s + j : s1 - 1];
            float w[8];
#pragma unroll
            for (int j = 0; j < 8; ++j) w[j] = (j < m) ? rdo[idx[j]] : 0.0f;
            float v[8];
#pragma unroll
            for (int j = 0; j < 8; ++j) v[j] = h[(size_t)idx[j] * 64 + lane];
#pragma unroll
            for (int j = 0; j < 8; ++j) acc = fmaf(v[j], w[j], acc);
        }
        p_o[(size_t)n * 64 + lane] = acc;
    } else {
        // p_i[n] = rdi[n] * sum_{row[e]=n} h[col[e]]
        int s0 = off_out[n], s1 = off_out[n + 1];
        float acc = 0.0f;
        for (int s = s0; s < s1; s += 8) {
            int m = s1 - s;
            int idx[8];
#pragma unroll
            for (int j = 0; j < 8; ++j) idx[j] = lst_out[(s + j < s1) ? s + j : s1 - 1];
            float v[8];
#pragma unroll
            for (int j = 0; j < 8; ++j) v[j] = h[(size_t)idx[j] * 64 + lane];
#pragma unroll
            for (int j = 0; j < 8; ++j) acc += (j < m) ? v[j] : 0.0f;
        }
        p_i[(size_t)n * 64 + lane] = acc * rdi[n];
    }
}

// h = sigmoid(x @ W (24x64) + b), one thread per (node, channel)
__global__ void __launch_bounds__(256) lin2_kernel(
        const float* __restrict__ x, const float* __restrict__ W,
        const float* __restrict__ b, float* __restrict__ h, int N) {
    __shared__ float Ws[24 * 64];
    __shared__ float bs[64];
    for (int i = threadIdx.x; i < 24 * 64; i += 256) Ws[i] = W[i];
    if (threadIdx.x < 64) bs[threadIdx.x] = b[threadIdx.x];
    __syncthreads();
    int gid = blockIdx.x * 256 + threadIdx.x;
    int n = gid >> 6;
    int c = gid & 63;
    if (n >= N) return;
    const float* xr = x + (size_t)n * 24;
    float acc = bs[c];
#pragma unroll
    for (int k = 0; k < 24; ++k) acc += xr[k] * Ws[k * 64 + c];
    h[(size_t)n * 64 + c] = sigmoid_f(acc);
}

// Build combined weights: Wc[192][128] = [A;B;C] x [z-gate | h-gate], bc[128]
__global__ void prep_kernel(const float* __restrict__ wz, const float* __restrict__ bz,
                            const float* __restrict__ wh, const float* __restrict__ bh,
                            float* __restrict__ Wc, float* __restrict__ bc) {
    int i = blockIdx.x * 256 + threadIdx.x;
    if (i < 128) bc[i] = (i < 64) ? bz[i] : bh[i - 64];
    if (i >= 192 * 128) return;
    int k = i >> 7;        // 0..191
    int c = i & 127;       // 0..127
    const float* w = (c < 64) ? wz : wh;
    int cc = c & 63;
    float v;
    if (k < 64)        v = w[(0 * 128 + k) * 64 + cc] + w[(2 * 128 + k) * 64 + cc];
    else if (k < 128)  v = w[(1 * 128 + (k - 64)) * 64 + cc];
    else               v = w[(3 * 128 + (k - 128)) * 64 + cc];
    Wc[i] = v;
}

// Fused gate GEMM + GRU combine + output projection.
__global__ void __launch_bounds__(256) gates_kernel(
        const float* __restrict__ h, const float* __restrict__ p_o,
        const float* __restrict__ p_i, const float* __restrict__ Wc,
        const float* __restrict__ bc, const float* __restrict__ wout,
        const float* __restrict__ bout, float* __restrict__ out, int N) {
    __shared__ float sW[64 * 128];   // K-chunk of weights; reused as s-tile later
    __shared__ float sIn[64 * 68];   // transposed input chunk [kk][node], pad 68
    __shared__ float sWO[64 * 12];

    const int t  = threadIdx.x;
    const int ng = t >> 4;           // 0..15: nodes ng*4..+4
    const int cg = t & 15;           // 0..15: channels cg*4..+4
    const int n0 = blockIdx.x * 64;

    float acc[4][8];
#pragma unroll
    for (int j = 0; j < 4; ++j) {
        float bz_ = bc[cg * 4 + j];
        float bh_ = bc[64 + cg * 4 + j];
#pragma unroll
        for (int i = 0; i < 4; ++i) { acc[i][j] = bz_; acc[i][4 + j] = bh_; }
    }
    for (int i = t; i < 64 * 12; i += 256) sWO[i] = wout[i];

    for (int kc = 0; kc < 3; ++kc) {
        const float* src = (kc == 0) ? h : ((kc == 1) ? p_o : p_i);
        __syncthreads();
        // stage inputs transposed: sIn[kk][node]
#pragma unroll
        for (int r = 0; r < 4; ++r) {
            int idx  = r * 256 + t;      // float4 index: 16 per node row
            int node = idx >> 4;
            int k4   = idx & 15;
            int nd   = min(n0 + node, N - 1);
            const float4 v = *(const float4*)(src + (size_t)nd * 64 + k4 * 4);
            sIn[(k4 * 4 + 0) * 68 + node] = v.x;
            sIn[(k4 * 4 + 1) * 68 + node] = v.y;
            sIn[(k4 * 4 + 2) * 68 + node] = v.z;
            sIn[(k4 * 4 + 3) * 68 + node] = v.w;
        }
        // stage weight chunk: sW[kk][c], 64x128
#pragma unroll
        for (int r = 0; r < 8; ++r) {
            int idx = r * 256 + t;       // float4 index: 32 per row
            int kk  = idx >> 5;
            int c4  = idx & 31;
            *(float4*)(sW + kk * 128 + c4 * 4) =
                *(const float4*)(Wc + (size_t)(kc * 64 + kk) * 128 + c4 * 4);
        }
        __syncthreads();
#pragma unroll 8
        for (int kk = 0; kk < 64; ++kk) {
            float4 a  = *(const float4*)(sIn + kk * 68 + ng * 4);
            float4 w0 = *(const float4*)(sW + kk * 128 + cg * 4);        // z cols
            float4 w1 = *(const float4*)(sW + kk * 128 + 64 + cg * 4);   // h cols
            float av[4] = {a.x, a.y, a.z, a.w};
            float wz_[4] = {w0.x, w0.y, w0.z, w0.w};
            float wh_[4] = {w1.x, w1.y, w1.z, w1.w};
#pragma unroll
            for (int i = 0; i < 4; ++i) {
#pragma unroll
                for (int j = 0; j < 4; ++j) {
                    acc[i][j]     = fmaf(av[i], wz_[j], acc[i][j]);
                    acc[i][4 + j] = fmaf(av[i], wh_[j], acc[i][4 + j]);
                }
            }
        }
    }

    // GRU combine in-register, s-tile to LDS (reusing sW space)
    __syncthreads();
    float* sS = sW;                  // [64][68]
#pragma unroll
    for (int i = 0; i < 4; ++i) {
        int node = ng * 4 + i;
        float4 sv;
        float* svp = (float*)&sv;
#pragma unroll
        for (int j = 0; j < 4; ++j) {
            float zv = sigmoid_f(acc[i][j]);
            float ht = tanh_f(acc[i][4 + j]);
            svp[j] = sigmoid_f((1.0f - zv) * ht);
        }
        *(float4*)(sS + node * 68 + cg * 4) = sv;
    }
    __syncthreads();

    // out[node][j] = s[node] . WO[:,j] + bout[j];  64*12 = 768 = 3*256 outputs
#pragma unroll
    for (int r = 0; r < 3; ++r) {
        int o    = r * 256 + t;
        int node = o / 12;
        int j    = o % 12;
        int n    = n0 + node;
        if (n >= N) continue;
        float a = bout[j];
#pragma unroll 8
        for (int c = 0; c < 64; ++c) a = fmaf(sS[node * 68 + c], sWO[c * 12 + j], a);
        out[(size_t)n * 12 + j] = a;
    }
}

extern "C" void kernel_launch(void* const* d_in, const int* in_sizes, int n_in,
                              void* d_out, int out_size, void* d_ws, size_t ws_size,
                              hipStream_t stream) {
    const float* x      = (const float*)d_in[0];
    const int*   ei     = (const int*)  d_in[1];
    const float* ew     = (const float*)d_in[2];
    const float* w_lin2 = (const float*)d_in[3];
    const float* b_lin2 = (const float*)d_in[4];
    const float* w_z    = (const float*)d_in[5];
    const float* b_z    = (const float*)d_in[6];
    // d_in[7], d_in[8]: w_r, b_r — dead (h0 == 0)
    const float* w_h    = (const float*)d_in[9];
    const float* b_h    = (const float*)d_in[10];
    const float* w_out  = (const float*)d_in[11];
    const float* b_out  = (const float*)d_in[12];

    int N = in_sizes[0] / 24;
    int E = in_sizes[1] / 2;
    const int* row = ei;
    const int* col = ei + E;
    int G = (N + 255) / 256;   // <= 512 required by scan2 (N <= 131072)

    float* ws   = (float*)d_ws;
    float* h    = ws;                          // N*64
    float* p_o  = h   + (size_t)N * 64;        // N*64
    float* p_i  = p_o + (size_t)N * 64;        // N*64
    float* Wc   = p_i + (size_t)N * 64;        // 192*128
    float* bc   = Wc  + 192 * 128;             // 128
    unsigned long long* pack_out = (unsigned long long*)(bc + 128);  // N (zeroed)
    unsigned long long* pack_in  = pack_out + N;                     // N (zeroed)
    float* rdo  = (float*)(pack_in + N);       // N
    float* rdi  = rdo + N;                     // N
    int* off_in  = (int*)(rdi + N);            // N+1
    int* off_out = off_in + N + 1;             // N+1
    int* slot_in  = off_out + N + 1;           // E
    int* slot_out = slot_in + E;               // E
    int* lst_in  = slot_out + E;               // E
    int* lst_out = lst_in + E;                 // E
    int* bsum_in  = lst_out + E;               // 512
    int* bsum_out = bsum_in + 512;             // 512

    // zero the packed histograms (contiguous, 16N bytes)
    hipMemsetAsync(pack_out, 0, (size_t)N * 2 * sizeof(unsigned long long), stream);

    prep_kernel<<<(192 * 128 + 255) / 256, 256, 0, stream>>>(w_z, b_z, w_h, b_h, Wc, bc);
    deg_hist_kernel<<<(E + 255) / 256, 256, 0, stream>>>(row, col, ew, pack_out, pack_in,
                                                         slot_out, slot_in, E);
    scan1_kernel<<<dim3(G, 2), 256, 0, stream>>>(pack_in, off_in, bsum_in,
                                                 pack_out, off_out, bsum_out, N);
    scan2_kernel<<<dim3(1, 2), 512, 0, stream>>>(bsum_in, off_in, bsum_out, off_out, G, N);
    scan3_kernel<<<dim3(G, 2), 256, 0, stream>>>(off_in, bsum_in, off_out, bsum_out,
                                                 pack_out, pack_in, rdo, rdi, N);
    lin2_kernel<<<(N * 64 + 255) / 256, 256, 0, stream>>>(x, w_lin2, b_lin2, h, N);
    fill_kernel<<<(E + 255) / 256, 256, 0, stream>>>(row, col, off_in, off_out,
                                                     slot_in, slot_out, lst_in, lst_out, E);
    gather_kernel<<<dim3((N + 3) / 4, 2), 256, 0, stream>>>(h, off_in, lst_in, rdo,
                                                            off_out, lst_out, rdi,
                                                            p_o, p_i, N);
    gates_kernel<<<(N + 63) / 64, 256, 0, stream>>>(h, p_o, p_i, Wc, bc,
                                                    w_out, b_out, (float*)d_out, N);
}

// Round 6
// 305.133 us; speedup vs baseline: 3.8252x; 1.0277x over previous
//
#include <hip/hip_runtime.h>

// ---------------------------------------------------------------------------
// RecurrentGNN (DCRNN single step), N=100000, E=800000, HID=64, OUT=12
// h0 == 0  =>  only k<64 rows of dconv weights matter; r-gate dead;
//              h_new = (1-z)*h_tilde.
// Round 1: fused gate GEMM (kz+kh+out-projection in one kernel).
// Round 2: CSR build + wave-per-node gather (no fp32 atomics).
// Round 3: MLP-unrolled gather + direction-parallel blocks.
// Round 4: packed u64 histogram atomic -> slot assignment; fill has 0 atomics.
// Round 5: gates GEMM restructured: 32-k chunks (28KB LDS -> ~5 blocks/CU),
//          node-major sIn (conflict-free staging), float4-along-k fragments.
// ---------------------------------------------------------------------------

__device__ __forceinline__ float sigmoid_f(float x) {
    return 1.0f / (1.0f + __expf(-x));
}
__device__ __forceinline__ float tanh_f(float x) {
    float ax = fabsf(x);
    float e = __expf(-2.0f * ax);
    float t = (1.0f - e) / (1.0f + e);
    return copysignf(t, x);
}

#define FIX_SCALE 1073741824.0f            // 2^30
#define FIX_INV   9.313225746154785e-10f   // 2^-30
#define FIX_MASK  0xFFFFFFFFFFFFull        // low 48 bits

// packed degree+count histogram; returned count = CSR slot for this edge
__global__ void __launch_bounds__(256) deg_hist_kernel(
        const int* __restrict__ row, const int* __restrict__ col,
        const float* __restrict__ ew,
        unsigned long long* __restrict__ pack_out,
        unsigned long long* __restrict__ pack_in,
        int* __restrict__ slot_out, int* __restrict__ slot_in, int E) {
    int e = blockIdx.x * 256 + threadIdx.x;
    if (e < E) {
        float w = ew[e];
        int r = row[e], c = col[e];
        unsigned long long fx = (unsigned long long)(w * FIX_SCALE + 0.5f);
        unsigned long long v = (1ull << 48) | fx;
        unsigned long long a = atomicAdd(&pack_out[r], v);
        unsigned long long b = atomicAdd(&pack_in[c], v);
        slot_out[e] = (int)(a >> 48);
        slot_in[e]  = (int)(b >> 48);
    }
}

// block-level exclusive scan of counts (y: 0=in, 1=out)
__global__ void __launch_bounds__(256) scan1_kernel(
        const unsigned long long* __restrict__ pi, int* __restrict__ oi, int* __restrict__ bi,
        const unsigned long long* __restrict__ po, int* __restrict__ oo, int* __restrict__ bo,
        int N) {
    const unsigned long long* pk = blockIdx.y ? po : pi;
    int* off = blockIdx.y ? oo : oi;
    int* bs  = blockIdx.y ? bo : bi;
    __shared__ int s[256];
    int t = threadIdx.x;
    int i = blockIdx.x * 256 + t;
    int v = (i < N) ? (int)(pk[i] >> 48) : 0;
    s[t] = v;
    __syncthreads();
    for (int d = 1; d < 256; d <<= 1) {
        int u = (t >= d) ? s[t - d] : 0;
        __syncthreads();
        s[t] += u;
        __syncthreads();
    }
    if (i < N) off[i] = s[t] - v;
    if (t == 255) bs[blockIdx.x] = s[255];
}

// scan of block sums (G <= 512), writes exclusive block offsets + total to off[N]
__global__ void __launch_bounds__(512) scan2_kernel(
        int* __restrict__ bi, int* __restrict__ oi,
        int* __restrict__ bo, int* __restrict__ oo, int G, int N) {
    int* bs  = blockIdx.y ? bo : bi;
    int* off = blockIdx.y ? oo : oi;
    __shared__ int s[512];
    int t = threadIdx.x;
    int v = (t < G) ? bs[t] : 0;
    s[t] = v;
    __syncthreads();
    for (int d = 1; d < 512; d <<= 1) {
        int u = (t >= d) ? s[t - d] : 0;
        __syncthreads();
        s[t] += u;
        __syncthreads();
    }
    if (t < G) bs[t] = s[t] - v;
    if (t == 511) off[N] = s[511];
}

// finalize offsets + reciprocal degrees from packed low bits
__global__ void __launch_bounds__(256) scan3_kernel(
        int* __restrict__ oi, const int* __restrict__ bi,
        int* __restrict__ oo, const int* __restrict__ bo,
        const unsigned long long* __restrict__ pack_out,
        const unsigned long long* __restrict__ pack_in,
        float* __restrict__ rdo, float* __restrict__ rdi, int N) {
    int i = blockIdx.x * 256 + threadIdx.x;
    if (i >= N) return;
    if (blockIdx.y == 0) {
        oi[i] += bi[i >> 8];
        rdo[i] = 1.0f / ((float)(pack_out[i] & FIX_MASK) * FIX_INV);
    } else {
        oo[i] += bo[i >> 8];
        rdi[i] = 1.0f / ((float)(pack_in[i] & FIX_MASK) * FIX_INV);
    }
}

// place edge endpoints at precomputed slots — no atomics
__global__ void __launch_bounds__(256) fill_kernel(
        const int* __restrict__ row, const int* __restrict__ col,
        const int* __restrict__ off_in, const int* __restrict__ off_out,
        const int* __restrict__ slot_in, const int* __restrict__ slot_out,
        int* __restrict__ lst_in, int* __restrict__ lst_out, int E) {
    int e = blockIdx.x * 256 + threadIdx.x;
    if (e < E) {
        int r = row[e], c = col[e];
        lst_in[off_in[c] + slot_in[e]] = r;
        lst_out[off_out[r] + slot_out[e]] = c;
    }
}

// wave per (node, direction); lane = channel. 8-edge chunks of independent
// loads to break the index->row dependent-latency chain.
__global__ void __launch_bounds__(256) gather_kernel(
        const float* __restrict__ h,
        const int* __restrict__ off_in, const int* __restrict__ lst_in,
        const float* __restrict__ rdo,
        const int* __restrict__ off_out, const int* __restrict__ lst_out,
        const float* __restrict__ rdi,
        float* __restrict__ p_o, float* __restrict__ p_i, int N) {
    int n = blockIdx.x * 4 + (threadIdx.x >> 6);
    if (n >= N) return;
    int lane = threadIdx.x & 63;

    if (blockIdx.y == 0) {
        // p_o[n] = sum_{col[e]=n} h[row[e]] * rdo[row[e]]
        int s0 = off_in[n], s1 = off_in[n + 1];
        float acc = 0.0f;
        for (int s = s0; s < s1; s += 8) {
            int m = s1 - s;
            int idx[8];
#pragma unroll
            for (int j = 0; j < 8; ++j) idx[j] = lst_in[(s + j < s1) ? s + j : s1 - 1];
            float w[8];
#pragma unroll
            for (int j = 0; j < 8; ++j) w[j] = (j < m) ? rdo[idx[j]] : 0.0f;
            float v[8];
#pragma unroll
            for (int j = 0; j < 8; ++j) v[j] = h[(size_t)idx[j] * 64 + lane];
#pragma unroll
            for (int j = 0; j < 8; ++j) acc = fmaf(v[j], w[j], acc);
        }
        p_o[(size_t)n * 64 + lane] = acc;
    } else {
        // p_i[n] = rdi[n] * sum_{row[e]=n} h[col[e]]
        int s0 = off_out[n], s1 = off_out[n + 1];
        float acc = 0.0f;
        for (int s = s0; s < s1; s += 8) {
            int m = s1 - s;
            int idx[8];
#pragma unroll
            for (int j = 0; j < 8; ++j) idx[j] = lst_out[(s + j < s1) ? s + j : s1 - 1];
            float v[8];
#pragma unroll
            for (int j = 0; j < 8; ++j) v[j] = h[(size_t)idx[j] * 64 + lane];
#pragma unroll
            for (int j = 0; j < 8; ++j) acc += (j < m) ? v[j] : 0.0f;
        }
        p_i[(size_t)n * 64 + lane] = acc * rdi[n];
    }
}

// h = sigmoid(x @ W (24x64) + b), one thread per (node, channel)
__global__ void __launch_bounds__(256) lin2_kernel(
        const float* __restrict__ x, const float* __restrict__ W,
        const float* __restrict__ b, float* __restrict__ h, int N) {
    __shared__ float Ws[24 * 64];
    __shared__ float bs[64];
    for (int i = threadIdx.x; i < 24 * 64; i += 256) Ws[i] = W[i];
    if (threadIdx.x < 64) bs[threadIdx.x] = b[threadIdx.x];
    __syncthreads();
    int gid = blockIdx.x * 256 + threadIdx.x;
    int n = gid >> 6;
    int c = gid & 63;
    if (n >= N) return;
    const float* xr = x + (size_t)n * 24;
    float acc = bs[c];
#pragma unroll
    for (int k = 0; k < 24; ++k) acc += xr[k] * Ws[k * 64 + c];
    h[(size_t)n * 64 + c] = sigmoid_f(acc);
}

// Build combined weights: Wc[192][128] = [A;B;C] x [z-gate | h-gate], bc[128]
__global__ void prep_kernel(const float* __restrict__ wz, const float* __restrict__ bz,
                            const float* __restrict__ wh, const float* __restrict__ bh,
                            float* __restrict__ Wc, float* __restrict__ bc) {
    int i = blockIdx.x * 256 + threadIdx.x;
    if (i < 128) bc[i] = (i < 64) ? bz[i] : bh[i - 64];
    if (i >= 192 * 128) return;
    int k = i >> 7;        // 0..191
    int c = i & 127;       // 0..127
    const float* w = (c < 64) ? wz : wh;
    int cc = c & 63;
    float v;
    if (k < 64)        v = w[(0 * 128 + k) * 64 + cc] + w[(2 * 128 + k) * 64 + cc];
    else if (k < 128)  v = w[(1 * 128 + (k - 64)) * 64 + cc];
    else               v = w[(3 * 128 + (k - 128)) * 64 + cc];
    Wc[i] = v;
}

// Fused gate GEMM + GRU combine + output projection.
// 64 nodes/block, 256 threads: ng=t>>4 (nodes ng*4..+4), cg=t&15
// (z-cols cg*4..+4 and h-cols 64+cg*4..+4 -> same channels in-thread).
// K processed in 6 chunks of 32 (3 sources x 2 halves). LDS 28KB.
__global__ void __launch_bounds__(256) gates_kernel(
        const float* __restrict__ h, const float* __restrict__ p_o,
        const float* __restrict__ p_i, const float* __restrict__ Wc,
        const float* __restrict__ bc, const float* __restrict__ wout,
        const float* __restrict__ bout, float* __restrict__ out, int N) {
    __shared__ float smem[32 * 128 + 64 * 36 + 64 * 12];  // 7168 floats = 28KB
    float* sW  = smem;                // [32][128]
    float* sIn = smem + 32 * 128;     // [64][36]  node-major, pad 36
    float* sWO = smem + 32 * 128 + 64 * 36;  // [64][12]

    const int t  = threadIdx.x;
    const int ng = t >> 4;           // 0..15
    const int cg = t & 15;           // 0..15
    const int n0 = blockIdx.x * 64;

    float acc[4][8];
#pragma unroll
    for (int j = 0; j < 4; ++j) {
        float bz_ = bc[cg * 4 + j];
        float bh_ = bc[64 + cg * 4 + j];
#pragma unroll
        for (int i = 0; i < 4; ++i) { acc[i][j] = bz_; acc[i][4 + j] = bh_; }
    }
    for (int i = t; i < 64 * 12; i += 256) sWO[i] = wout[i];

    for (int kc = 0; kc < 6; ++kc) {
        const int srci = kc >> 1;
        const float* src = (srci == 0) ? h : ((srci == 1) ? p_o : p_i);
        const int koff = (kc & 1) * 32;          // k offset within source row
        __syncthreads();
        // stage A node-major: sIn[node][0..31], coalesced float4, no transpose
#pragma unroll
        for (int r = 0; r < 2; ++r) {
            int idx  = r * 256 + t;      // 0..511
            int node = idx >> 3;         // 0..63
            int k4   = idx & 7;          // float4 index within 32 floats
            int nd   = min(n0 + node, N - 1);
            *(float4*)(sIn + node * 36 + k4 * 4) =
                *(const float4*)(src + (size_t)nd * 64 + koff + k4 * 4);
        }
        // stage W chunk: sW[kk][c], 32x128
#pragma unroll
        for (int r = 0; r < 4; ++r) {
            int idx = r * 256 + t;       // 0..1023
            int kk  = idx >> 5;          // 0..31
            int c4  = idx & 31;
            *(float4*)(sW + kk * 128 + c4 * 4) =
                *(const float4*)(Wc + (size_t)(kc * 32 + kk) * 128 + c4 * 4);
        }
        __syncthreads();
#pragma unroll 4
        for (int kk4 = 0; kk4 < 8; ++kk4) {
            float4 a0 = *(const float4*)(sIn + (ng * 4 + 0) * 36 + kk4 * 4);
            float4 a1 = *(const float4*)(sIn + (ng * 4 + 1) * 36 + kk4 * 4);
            float4 a2 = *(const float4*)(sIn + (ng * 4 + 2) * 36 + kk4 * 4);
            float4 a3 = *(const float4*)(sIn + (ng * 4 + 3) * 36 + kk4 * 4);
            const float av[4][4] = {{a0.x, a0.y, a0.z, a0.w},
                                    {a1.x, a1.y, a1.z, a1.w},
                                    {a2.x, a2.y, a2.z, a2.w},
                                    {a3.x, a3.y, a3.z, a3.w}};
#pragma unroll
            for (int q = 0; q < 4; ++q) {
                float4 w0 = *(const float4*)(sW + (kk4 * 4 + q) * 128 + cg * 4);
                float4 w1 = *(const float4*)(sW + (kk4 * 4 + q) * 128 + 64 + cg * 4);
                const float wz_[4] = {w0.x, w0.y, w0.z, w0.w};
                const float wh_[4] = {w1.x, w1.y, w1.z, w1.w};
#pragma unroll
                for (int i = 0; i < 4; ++i) {
#pragma unroll
                    for (int j = 0; j < 4; ++j) {
                        acc[i][j]     = fmaf(av[i][q], wz_[j], acc[i][j]);
                        acc[i][4 + j] = fmaf(av[i][q], wh_[j], acc[i][4 + j]);
                    }
                }
            }
        }
    }

    // GRU combine in-register, s-tile to LDS (overlay smem, stride 68)
    __syncthreads();
    float* sS = smem;                // [64][68] = 4352 floats (< 6400 used)
#pragma unroll
    for (int i = 0; i < 4; ++i) {
        int node = ng * 4 + i;
        float4 sv;
        float* svp = (float*)&sv;
#pragma unroll
        for (int j = 0; j < 4; ++j) {
            float zv = sigmoid_f(acc[i][j]);
            float ht = tanh_f(acc[i][4 + j]);
            svp[j] = sigmoid_f((1.0f - zv) * ht);
        }
        *(float4*)(sS + node * 68 + cg * 4) = sv;
    }
    __syncthreads();

    // out[node][j] = s[node] . WO[:,j] + bout[j];  64*12 = 768 = 3*256 outputs
#pragma unroll
    for (int r = 0; r < 3; ++r) {
        int o    = r * 256 + t;
        int node = o / 12;
        int j    = o % 12;
        int n    = n0 + node;
        if (n >= N) continue;
        float a = bout[j];
#pragma unroll 8
        for (int c = 0; c < 64; ++c) a = fmaf(sS[node * 68 + c], sWO[c * 12 + j], a);
        out[(size_t)n * 12 + j] = a;
    }
}

extern "C" void kernel_launch(void* const* d_in, const int* in_sizes, int n_in,
                              void* d_out, int out_size, void* d_ws, size_t ws_size,
                              hipStream_t stream) {
    const float* x      = (const float*)d_in[0];
    const int*   ei     = (const int*)  d_in[1];
    const float* ew     = (const float*)d_in[2];
    const float* w_lin2 = (const float*)d_in[3];
    const float* b_lin2 = (const float*)d_in[4];
    const float* w_z    = (const float*)d_in[5];
    const float* b_z    = (const float*)d_in[6];
    // d_in[7], d_in[8]: w_r, b_r — dead (h0 == 0)
    const float* w_h    = (const float*)d_in[9];
    const float* b_h    = (const float*)d_in[10];
    const float* w_out  = (const float*)d_in[11];
    const float* b_out  = (const float*)d_in[12];

    int N = in_sizes[0] / 24;
    int E = in_sizes[1] / 2;
    const int* row = ei;
    const int* col = ei + E;
    int G = (N + 255) / 256;   // <= 512 required by scan2 (N <= 131072)

    float* ws   = (float*)d_ws;
    float* h    = ws;                          // N*64
    float* p_o  = h   + (size_t)N * 64;        // N*64
    float* p_i  = p_o + (size_t)N * 64;        // N*64
    float* Wc   = p_i + (size_t)N * 64;        // 192*128
    float* bc   = Wc  + 192 * 128;             // 128
    unsigned long long* pack_out = (unsigned long long*)(bc + 128);  // N (zeroed)
    unsigned long long* pack_in  = pack_out + N;                     // N (zeroed)
    float* rdo  = (float*)(pack_in + N);       // N
    float* rdi  = rdo + N;                     // N
    int* off_in  = (int*)(rdi + N);            // N+1
    int* off_out = off_in + N + 1;             // N+1
    int* slot_in  = off_out + N + 1;           // E
    int* slot_out = slot_in + E;               // E
    int* lst_in  = slot_out + E;               // E
    int* lst_out = lst_in + E;                 // E
    int* bsum_in  = lst_out + E;               // 512
    int* bsum_out = bsum_in + 512;             // 512

    // zero the packed histograms (contiguous, 16N bytes)
    hipMemsetAsync(pack_out, 0, (size_t)N * 2 * sizeof(unsigned long long), stream);

    prep_kernel<<<(192 * 128 + 255) / 256, 256, 0, stream>>>(w_z, b_z, w_h, b_h, Wc, bc);
    deg_hist_kernel<<<(E + 255) / 256, 256, 0, stream>>>(row, col, ew, pack_out, pack_in,
                                                         slot_out, slot_in, E);
    scan1_kernel<<<dim3(G, 2), 256, 0, stream>>>(pack_in, off_in, bsum_in,
                                                 pack_out, off_out, bsum_out, N);
    scan2_kernel<<<dim3(1, 2), 512, 0, stream>>>(bsum_in, off_in, bsum_out, off_out, G, N);
    scan3_kernel<<<dim3(G, 2), 256, 0, stream>>>(off_in, bsum_in, off_out, bsum_out,
                                                 pack_out, pack_in, rdo, rdi, N);
    lin2_kernel<<<(N * 64 + 255) / 256, 256, 0, stream>>>(x, w_lin2, b_lin2, h, N);
    fill_kernel<<<(E + 255) / 256, 256, 0, stream>>>(row, col, off_in, off_out,
                                                     slot_in, slot_out, lst_in, lst_out, E);
    gather_kernel<<<dim3((N + 3) / 4, 2), 256, 0, stream>>>(h, off_in, lst_in, rdo,
                                                            off_out, lst_out, rdi,
                                                            p_o, p_i, N);
    gates_kernel<<<(N + 63) / 64, 256, 0, stream>>>(h, p_o, p_i, Wc, bc,
                                                    w_out, b_out, (float*)d_out, N);
}

// Round 7
// 241.481 us; speedup vs baseline: 4.8335x; 1.2636x over previous
//
#include <hip/hip_runtime.h>

// ---------------------------------------------------------------------------
// RecurrentGNN (DCRNN single step), N=100000, E=800000, HID=64, OUT=12
// h0 == 0  =>  only k<64 rows of dconv weights matter; r-gate dead;
//              h_new = (1-z)*h_tilde.
// Round 4: packed u64 histogram atomic -> slot assignment; fill has 0 atomics.
// Round 6: h/p_o/p_i in bf16; gates GEMM on MFMA (16x16x32 bf16) with
//          fragment-packed weights (no LDS in GEMM); deg_hist+lin2+prep
//          merged into one dispatch (atomic-bound + VALU-bound overlap).
// ---------------------------------------------------------------------------

typedef unsigned long long ull;
typedef unsigned short ushort;
typedef __attribute__((ext_vector_type(8))) short bf16x8;
typedef __attribute__((ext_vector_type(4))) float f32x4;

__device__ __forceinline__ float sigmoid_f(float x) {
    return 1.0f / (1.0f + __expf(-x));
}
__device__ __forceinline__ float tanh_f(float x) {
    float ax = fabsf(x);
    float e = __expf(-2.0f * ax);
    float t = (1.0f - e) / (1.0f + e);
    return copysignf(t, x);
}
__device__ __forceinline__ ushort f2bf(float f) {   // round-to-nearest-even
    unsigned u = __float_as_uint(f);
    return (ushort)((u + 0x7FFF + ((u >> 16) & 1)) >> 16);
}
__device__ __forceinline__ float bf2f(ushort s) {
    return __uint_as_float(((unsigned)s) << 16);
}

#define FIX_SCALE 1073741824.0f            // 2^30
#define FIX_INV   9.313225746154785e-10f   // 2^-30
#define FIX_MASK  0xFFFFFFFFFFFFull        // low 48 bits

// --- merged: deg/slot histogram  |  lin2 (h bf16)  |  weight prep (packed) --
__global__ void __launch_bounds__(256) phase1_kernel(
        const int* __restrict__ row, const int* __restrict__ col,
        const float* __restrict__ ew,
        ull* __restrict__ pack_out, ull* __restrict__ pack_in,
        int* __restrict__ slot_out, int* __restrict__ slot_in, int E,
        const float* __restrict__ x, const float* __restrict__ Wl,
        const float* __restrict__ bl, ushort* __restrict__ hb, int N,
        const float* __restrict__ wz, const float* __restrict__ bz,
        const float* __restrict__ wh, const float* __restrict__ bh,
        ushort* __restrict__ Wp, float* __restrict__ bc, int EB, int LB) {
    __shared__ float Ws[24 * 64];
    __shared__ float bs[64];
    const int bx = blockIdx.x;
    const int t  = threadIdx.x;
    if (bx < EB) {
        // packed degree+count histogram; returned count = CSR slot
        int e = bx * 256 + t;
        if (e < E) {
            float w = ew[e];
            int r = row[e], c = col[e];
            ull fx = (ull)(w * FIX_SCALE + 0.5f);
            ull v = (1ull << 48) | fx;
            ull a = atomicAdd(&pack_out[r], v);
            ull b = atomicAdd(&pack_in[c], v);
            slot_out[e] = (int)(a >> 48);
            slot_in[e]  = (int)(b >> 48);
        }
        return;
    }
    if (bx < EB + LB) {
        // h = sigmoid(x @ Wl + bl) -> bf16
        for (int i = t; i < 24 * 64; i += 256) Ws[i] = Wl[i];
        if (t < 64) bs[t] = bl[t];
        __syncthreads();
        int gid = (bx - EB) * 256 + t;
        int n = gid >> 6;
        int c = gid & 63;
        if (n >= N) return;
        const float* xr = x + (size_t)n * 24;
        float acc = bs[c];
#pragma unroll
        for (int k = 0; k < 24; ++k) acc += xr[k] * Ws[k * 64 + c];
        hb[(size_t)n * 64 + c] = f2bf(sigmoid_f(acc));
        return;
    }
    // weight prep: pack B fragments for mfma_f32_16x16x32_bf16.
    // Wp[((kt*8+ct)*64+lane)*8 + j] = B[k=kt*32+8*(lane>>4)+j][c=ct*16+(lane&15)]
    int bx2 = bx - EB - LB;
    int i = bx2 * 256 + t;
    if (bx2 == 0 && t < 128) bc[t] = (t < 64) ? bz[t] : bh[t - 64];
    if (i >= 6 * 8 * 64 * 8) return;
    int j    = i & 7;
    int lane = (i >> 3) & 63;
    int ct   = (i >> 9) & 7;
    int kt   = i >> 12;
    int k = kt * 32 + 8 * (lane >> 4) + j;
    int c = ct * 16 + (lane & 15);
    const float* w = (c < 64) ? wz : wh;
    int cc = c & 63;
    float v;
    if (k < 64)        v = w[(0 * 128 + k) * 64 + cc] + w[(2 * 128 + k) * 64 + cc];
    else if (k < 128)  v = w[(1 * 128 + (k - 64)) * 64 + cc];
    else               v = w[(3 * 128 + (k - 128)) * 64 + cc];
    Wp[i] = f2bf(v);
}

// block-level exclusive scan of counts (y: 0=in, 1=out)
__global__ void __launch_bounds__(256) scan1_kernel(
        const ull* __restrict__ pi, int* __restrict__ oi, int* __restrict__ bi,
        const ull* __restrict__ po, int* __restrict__ oo, int* __restrict__ bo,
        int N) {
    const ull* pk = blockIdx.y ? po : pi;
    int* off = blockIdx.y ? oo : oi;
    int* bs  = blockIdx.y ? bo : bi;
    __shared__ int s[256];
    int t = threadIdx.x;
    int i = blockIdx.x * 256 + t;
    int v = (i < N) ? (int)(pk[i] >> 48) : 0;
    s[t] = v;
    __syncthreads();
    for (int d = 1; d < 256; d <<= 1) {
        int u = (t >= d) ? s[t - d] : 0;
        __syncthreads();
        s[t] += u;
        __syncthreads();
    }
    if (i < N) off[i] = s[t] - v;
    if (t == 255) bs[blockIdx.x] = s[255];
}

__global__ void __launch_bounds__(512) scan2_kernel(
        int* __restrict__ bi, int* __restrict__ oi,
        int* __restrict__ bo, int* __restrict__ oo, int G, int N) {
    int* bs  = blockIdx.y ? bo : bi;
    int* off = blockIdx.y ? oo : oi;
    __shared__ int s[512];
    int t = threadIdx.x;
    int v = (t < G) ? bs[t] : 0;
    s[t] = v;
    __syncthreads();
    for (int d = 1; d < 512; d <<= 1) {
        int u = (t >= d) ? s[t - d] : 0;
        __syncthreads();
        s[t] += u;
        __syncthreads();
    }
    if (t < G) bs[t] = s[t] - v;
    if (t == 511) off[N] = s[511];
}

__global__ void __launch_bounds__(256) scan3_kernel(
        int* __restrict__ oi, const int* __restrict__ bi,
        int* __restrict__ oo, const int* __restrict__ bo,
        const ull* __restrict__ pack_out, const ull* __restrict__ pack_in,
        float* __restrict__ rdo, float* __restrict__ rdi, int N) {
    int i = blockIdx.x * 256 + threadIdx.x;
    if (i >= N) return;
    if (blockIdx.y == 0) {
        oi[i] += bi[i >> 8];
        rdo[i] = 1.0f / ((float)(pack_out[i] & FIX_MASK) * FIX_INV);
    } else {
        oo[i] += bo[i >> 8];
        rdi[i] = 1.0f / ((float)(pack_in[i] & FIX_MASK) * FIX_INV);
    }
}

// place edge endpoints at precomputed slots — no atomics
__global__ void __launch_bounds__(256) fill_kernel(
        const int* __restrict__ row, const int* __restrict__ col,
        const int* __restrict__ off_in, const int* __restrict__ off_out,
        const int* __restrict__ slot_in, const int* __restrict__ slot_out,
        int* __restrict__ lst_in, int* __restrict__ lst_out, int E) {
    int e = blockIdx.x * 256 + threadIdx.x;
    if (e < E) {
        int r = row[e], c = col[e];
        lst_in[off_in[c] + slot_in[e]] = r;
        lst_out[off_out[r] + slot_out[e]] = c;
    }
}

// wave per (node, direction); lane = channel; bf16 rows (128B = 1 line/row)
__global__ void __launch_bounds__(256) gather_kernel(
        const ushort* __restrict__ hb,
        const int* __restrict__ off_in, const int* __restrict__ lst_in,
        const float* __restrict__ rdo,
        const int* __restrict__ off_out, const int* __restrict__ lst_out,
        const float* __restrict__ rdi,
        ushort* __restrict__ pob, ushort* __restrict__ pib, int N) {
    int n = blockIdx.x * 4 + (threadIdx.x >> 6);
    if (n >= N) return;
    int lane = threadIdx.x & 63;

    if (blockIdx.y == 0) {
        int s0 = off_in[n], s1 = off_in[n + 1];
        float acc = 0.0f;
        for (int s = s0; s < s1; s += 8) {
            int m = s1 - s;
            int idx[8];
#pragma unroll
            for (int j = 0; j < 8; ++j) idx[j] = lst_in[(s + j < s1) ? s + j : s1 - 1];
            float w[8];
#pragma unroll
            for (int j = 0; j < 8; ++j) w[j] = (j < m) ? rdo[idx[j]] : 0.0f;
            float v[8];
#pragma unroll
            for (int j = 0; j < 8; ++j) v[j] = bf2f(hb[(size_t)idx[j] * 64 + lane]);
#pragma unroll
            for (int j = 0; j < 8; ++j) acc = fmaf(v[j], w[j], acc);
        }
        pob[(size_t)n * 64 + lane] = f2bf(acc);
    } else {
        int s0 = off_out[n], s1 = off_out[n + 1];
        float acc = 0.0f;
        for (int s = s0; s < s1; s += 8) {
            int m = s1 - s;
            int idx[8];
#pragma unroll
            for (int j = 0; j < 8; ++j) idx[j] = lst_out[(s + j < s1) ? s + j : s1 - 1];
            float v[8];
#pragma unroll
            for (int j = 0; j < 8; ++j) v[j] = bf2f(hb[(size_t)idx[j] * 64 + lane]);
#pragma unroll
            for (int j = 0; j < 8; ++j) acc += (j < m) ? v[j] : 0.0f;
        }
        pib[(size_t)n * 64 + lane] = f2bf(acc * rdi[n]);
    }
}

// MFMA gate GEMM + in-register GRU combine + output projection.
// 64 nodes/block, 4 waves; wave w: nodes 16w..16w+15 x all 128 cols.
// A frag: per-lane 16B from bf16 row (row=lane&15, k=8*(lane>>4)+j).
// B frag: prep-packed, per-lane 16B coalesced.
// D tile ct (cols 16ct..+16): col=lane&15, node_row=4*(lane>>4)+reg.
__global__ void __launch_bounds__(256) gates_kernel(
        const ushort* __restrict__ hb, const ushort* __restrict__ pob,
        const ushort* __restrict__ pib, const ushort* __restrict__ Wp,
        const float* __restrict__ bc, const float* __restrict__ wout,
        const float* __restrict__ bout, float* __restrict__ out, int N) {
    __shared__ float sS[64 * 68];
    __shared__ float sWO[64 * 12];
    const int t    = threadIdx.x;
    const int w    = t >> 6;
    const int lane = t & 63;
    const int n0   = blockIdx.x * 64;

    for (int i = t; i < 64 * 12; i += 256) sWO[i] = wout[i];

    f32x4 acc[8];
#pragma unroll
    for (int ct = 0; ct < 8; ++ct) {
        float bcv = bc[ct * 16 + (lane & 15)];
        acc[ct] = (f32x4){bcv, bcv, bcv, bcv};
    }

    int arow = n0 + w * 16 + (lane & 15);
    if (arow >= N) arow = N - 1;
    const int g8 = (lane >> 4) * 8;
    const ushort* const srcs[3] = {hb, pob, pib};

#pragma unroll
    for (int kc = 0; kc < 6; ++kc) {
        const ushort* src = srcs[kc >> 1];
        bf16x8 a = *(const bf16x8*)(src + (size_t)arow * 64 + (kc & 1) * 32 + g8);
#pragma unroll
        for (int ct = 0; ct < 8; ++ct) {
            bf16x8 b = *(const bf16x8*)(Wp + (size_t)((kc * 8 + ct) * 64 + lane) * 8);
            acc[ct] = __builtin_amdgcn_mfma_f32_16x16x32_bf16(a, b, acc[ct], 0, 0, 0);
        }
    }

    // GRU combine: z tile ct pairs with h tile ct+4 (same lane/reg -> same
    // node & channel). s -> LDS for the 64->12 projection.
    const int rowbase = w * 16 + (lane >> 4) * 4;
    const int colbase = lane & 15;
#pragma unroll
    for (int ct = 0; ct < 4; ++ct) {
#pragma unroll
        for (int r = 0; r < 4; ++r) {
            float zv = sigmoid_f(acc[ct][r]);
            float ht = tanh_f(acc[ct + 4][r]);
            sS[(rowbase + r) * 68 + ct * 16 + colbase] =
                sigmoid_f((1.0f - zv) * ht);
        }
    }
    __syncthreads();

    // out[node][j] = s[node] . WO[:,j] + bout[j]
#pragma unroll
    for (int rr = 0; rr < 3; ++rr) {
        int o = rr * 256 + t;
        int node = o / 12;
        int j = o % 12;
        int n = n0 + node;
        if (n >= N) continue;
        float a = bout[j];
#pragma unroll 8
        for (int c2 = 0; c2 < 64; ++c2) a = fmaf(sS[node * 68 + c2], sWO[c2 * 12 + j], a);
        out[(size_t)n * 12 + j] = a;
    }
}

extern "C" void kernel_launch(void* const* d_in, const int* in_sizes, int n_in,
                              void* d_out, int out_size, void* d_ws, size_t ws_size,
                              hipStream_t stream) {
    const float* x      = (const float*)d_in[0];
    const int*   ei     = (const int*)  d_in[1];
    const float* ew     = (const float*)d_in[2];
    const float* w_lin2 = (const float*)d_in[3];
    const float* b_lin2 = (const float*)d_in[4];
    const float* w_z    = (const float*)d_in[5];
    const float* b_z    = (const float*)d_in[6];
    // d_in[7], d_in[8]: w_r, b_r — dead (h0 == 0)
    const float* w_h    = (const float*)d_in[9];
    const float* b_h    = (const float*)d_in[10];
    const float* w_out  = (const float*)d_in[11];
    const float* b_out  = (const float*)d_in[12];

    int N = in_sizes[0] / 24;
    int E = in_sizes[1] / 2;
    const int* row = ei;
    const int* col = ei + E;
    int G = (N + 255) / 256;   // <= 512 required by scan2

    ushort* hb  = (ushort*)d_ws;               // N*64 bf16
    ushort* pob = hb  + (size_t)N * 64;        // N*64 bf16
    ushort* pib = pob + (size_t)N * 64;        // N*64 bf16
    ushort* Wp  = pib + (size_t)N * 64;        // 6*8*64*8 = 24576 bf16 (packed frags)
    float*  bc  = (float*)(Wp + 24576);        // 128
    ull* pack_out = (ull*)(bc + 128);          // N (zeroed)
    ull* pack_in  = pack_out + N;              // N (zeroed)
    float* rdo  = (float*)(pack_in + N);       // N
    float* rdi  = rdo + N;                     // N
    int* off_in  = (int*)(rdi + N);            // N+1
    int* off_out = off_in + N + 1;             // N+1
    int* slot_in  = off_out + N + 1;           // E
    int* slot_out = slot_in + E;               // E
    int* lst_in  = slot_out + E;               // E
    int* lst_out = lst_in + E;                 // E
    int* bsum_in  = lst_out + E;               // 512
    int* bsum_out = bsum_in + 512;             // 512

    hipMemsetAsync(pack_out, 0, (size_t)N * 2 * sizeof(ull), stream);

    int EB = (E + 255) / 256;
    int LB = (N * 64 + 255) / 256;
    int PB = (6 * 8 * 64 * 8 + 255) / 256;
    phase1_kernel<<<EB + LB + PB, 256, 0, stream>>>(
        row, col, ew, pack_out, pack_in, slot_out, slot_in, E,
        x, w_lin2, b_lin2, hb, N,
        w_z, b_z, w_h, b_h, Wp, bc, EB, LB);
    scan1_kernel<<<dim3(G, 2), 256, 0, stream>>>(pack_in, off_in, bsum_in,
                                                 pack_out, off_out, bsum_out, N);
    scan2_kernel<<<dim3(1, 2), 512, 0, stream>>>(bsum_in, off_in, bsum_out, off_out, G, N);
    scan3_kernel<<<dim3(G, 2), 256, 0, stream>>>(off_in, bsum_in, off_out, bsum_out,
                                                 pack_out, pack_in, rdo, rdi, N);
    fill_kernel<<<(E + 255) / 256, 256, 0, stream>>>(row, col, off_in, off_out,
                                                     slot_in, slot_out, lst_in, lst_out, E);
    gather_kernel<<<dim3((N + 3) / 4, 2), 256, 0, stream>>>(hb, off_in, lst_in, rdo,
                                                            off_out, lst_out, rdi,
                                                            pob, pib, N);
    gates_kernel<<<(N + 63) / 64, 256, 0, stream>>>(hb, pob, pib, Wp, bc,
                                                    w_out, b_out, (float*)d_out, N);
}

// Round 8
// 231.058 us; speedup vs baseline: 5.0515x; 1.0451x over previous
//
#include <hip/hip_runtime.h>

// ---------------------------------------------------------------------------
// RecurrentGNN (DCRNN single step), N=100000, E=800000, HID=64, OUT=12
// h0 == 0  =>  only k<64 rows of dconv weights matter; r-gate dead;
//              h_new = (1-z)*h_tilde.
// Round 6: h/p in bf16; gates on MFMA with fragment-packed weights.
// Round 7: histogram atomics shrunk to u32 count-only (2/edge); edge weights
//          ride in the CSR word ((idx<<15)|fix14(w)); weighted degrees via
//          atomic-free CSR segment sums (deg_kernel).
// ---------------------------------------------------------------------------

typedef unsigned long long ull;
typedef unsigned short ushort;
typedef unsigned int uint;
typedef __attribute__((ext_vector_type(8))) short bf16x8;
typedef __attribute__((ext_vector_type(4))) float f32x4;

__device__ __forceinline__ float sigmoid_f(float x) {
    return 1.0f / (1.0f + __expf(-x));
}
__device__ __forceinline__ float tanh_f(float x) {
    float ax = fabsf(x);
    float e = __expf(-2.0f * ax);
    float t = (1.0f - e) / (1.0f + e);
    return copysignf(t, x);
}
__device__ __forceinline__ ushort f2bf(float f) {   // round-to-nearest-even
    unsigned u = __float_as_uint(f);
    return (ushort)((u + 0x7FFF + ((u >> 16) & 1)) >> 16);
}
__device__ __forceinline__ float bf2f(ushort s) {
    return __uint_as_float(((unsigned)s) << 16);
}

// --- merged: count histogram (u32) | lin2 (h bf16) | weight prep (packed) ---
__global__ void __launch_bounds__(256) phase1_kernel(
        const int* __restrict__ row, const int* __restrict__ col,
        uint* __restrict__ cnt_out, uint* __restrict__ cnt_in,
        int* __restrict__ slot_out, int* __restrict__ slot_in, int E,
        const float* __restrict__ x, const float* __restrict__ Wl,
        const float* __restrict__ bl, ushort* __restrict__ hb, int N,
        const float* __restrict__ wz, const float* __restrict__ bz,
        const float* __restrict__ wh, const float* __restrict__ bh,
        ushort* __restrict__ Wp, float* __restrict__ bc, int EB, int LB) {
    __shared__ float Ws[24 * 64];
    __shared__ float bs[64];
    const int bx = blockIdx.x;
    const int t  = threadIdx.x;
    if (bx < EB) {
        // count histogram; returned old count = CSR slot for this edge
        int e = bx * 256 + t;
        if (e < E) {
            int r = row[e], c = col[e];
            slot_out[e] = (int)atomicAdd(&cnt_out[r], 1u);
            slot_in[e]  = (int)atomicAdd(&cnt_in[c], 1u);
        }
        return;
    }
    if (bx < EB + LB) {
        // h = sigmoid(x @ Wl + bl) -> bf16
        for (int i = t; i < 384; i += 256)
            ((float4*)Ws)[i] = ((const float4*)Wl)[i];
        if (t < 64) bs[t] = bl[t];
        __syncthreads();
        int gid = (bx - EB) * 256 + t;
        int n = gid >> 6;
        int c = gid & 63;
        if (n >= N) return;
        const float* xr = x + (size_t)n * 24;
        float acc = bs[c];
#pragma unroll
        for (int k4 = 0; k4 < 6; ++k4) {
            float4 xv = *(const float4*)(xr + k4 * 4);
            acc = fmaf(xv.x, Ws[(k4 * 4 + 0) * 64 + c], acc);
            acc = fmaf(xv.y, Ws[(k4 * 4 + 1) * 64 + c], acc);
            acc = fmaf(xv.z, Ws[(k4 * 4 + 2) * 64 + c], acc);
            acc = fmaf(xv.w, Ws[(k4 * 4 + 3) * 64 + c], acc);
        }
        hb[(size_t)n * 64 + c] = f2bf(sigmoid_f(acc));
        return;
    }
    // weight prep: pack B fragments for mfma_f32_16x16x32_bf16.
    // Wp[((kt*8+ct)*64+lane)*8 + j] = B[k=kt*32+8*(lane>>4)+j][c=ct*16+(lane&15)]
    int bx2 = bx - EB - LB;
    int i = bx2 * 256 + t;
    if (bx2 == 0 && t < 128) bc[t] = (t < 64) ? bz[t] : bh[t - 64];
    if (i >= 6 * 8 * 64 * 8) return;
    int j    = i & 7;
    int lane = (i >> 3) & 63;
    int ct   = (i >> 9) & 7;
    int kt   = i >> 12;
    int k = kt * 32 + 8 * (lane >> 4) + j;
    int c = ct * 16 + (lane & 15);
    const float* w = (c < 64) ? wz : wh;
    int cc = c & 63;
    float v;
    if (k < 64)        v = w[(0 * 128 + k) * 64 + cc] + w[(2 * 128 + k) * 64 + cc];
    else if (k < 128)  v = w[(1 * 128 + (k - 64)) * 64 + cc];
    else               v = w[(3 * 128 + (k - 128)) * 64 + cc];
    Wp[i] = f2bf(v);
}

// block-level exclusive scan of counts (y: 0=in, 1=out)
__global__ void __launch_bounds__(256) scan1_kernel(
        const uint* __restrict__ ci, int* __restrict__ oi, int* __restrict__ bi,
        const uint* __restrict__ co, int* __restrict__ oo, int* __restrict__ bo,
        int N) {
    const uint* cnt = blockIdx.y ? co : ci;
    int* off = blockIdx.y ? oo : oi;
    int* bs  = blockIdx.y ? bo : bi;
    __shared__ int s[256];
    int t = threadIdx.x;
    int i = blockIdx.x * 256 + t;
    int v = (i < N) ? (int)cnt[i] : 0;
    s[t] = v;
    __syncthreads();
    for (int d = 1; d < 256; d <<= 1) {
        int u = (t >= d) ? s[t - d] : 0;
        __syncthreads();
        s[t] += u;
        __syncthreads();
    }
    if (i < N) off[i] = s[t] - v;
    if (t == 255) bs[blockIdx.x] = s[255];
}

__global__ void __launch_bounds__(512) scan2_kernel(
        int* __restrict__ bi, int* __restrict__ oi,
        int* __restrict__ bo, int* __restrict__ oo, int G, int N) {
    int* bs  = blockIdx.y ? bo : bi;
    int* off = blockIdx.y ? oo : oi;
    __shared__ int s[512];
    int t = threadIdx.x;
    int v = (t < G) ? bs[t] : 0;
    s[t] = v;
    __syncthreads();
    for (int d = 1; d < 512; d <<= 1) {
        int u = (t >= d) ? s[t - d] : 0;
        __syncthreads();
        s[t] += u;
        __syncthreads();
    }
    if (t < G) bs[t] = s[t] - v;
    if (t == 511) off[N] = s[511];
}

__global__ void __launch_bounds__(256) scan3_kernel(
        int* __restrict__ oi, const int* __restrict__ bi,
        int* __restrict__ oo, const int* __restrict__ bo, int N) {
    int i = blockIdx.x * 256 + threadIdx.x;
    if (i >= N) return;
    if (blockIdx.y == 0) oi[i] += bi[i >> 8];
    else                 oo[i] += bo[i >> 8];
}

// place packed (idx<<15 | fix14(w)) at precomputed slots — no atomics
__global__ void __launch_bounds__(256) fill_kernel(
        const int* __restrict__ row, const int* __restrict__ col,
        const float* __restrict__ ew,
        const int* __restrict__ off_in, const int* __restrict__ off_out,
        const int* __restrict__ slot_in, const int* __restrict__ slot_out,
        uint* __restrict__ pk_in, uint* __restrict__ pk_out, int E) {
    int e = blockIdx.x * 256 + threadIdx.x;
    if (e < E) {
        int r = row[e], c = col[e];
        uint w15 = (uint)(ew[e] * 16384.0f + 0.5f);
        pk_in[off_in[c] + slot_in[e]]   = ((uint)r << 15) | w15;
        pk_out[off_out[r] + slot_out[e]] = ((uint)c << 15) | w15;
    }
}

// weighted degrees via CSR segment sums (atomic-free)
__global__ void __launch_bounds__(256) deg_kernel(
        const int* __restrict__ off_in, const uint* __restrict__ pk_in,
        float* __restrict__ rdi,
        const int* __restrict__ off_out, const uint* __restrict__ pk_out,
        float* __restrict__ rdo, int N) {
    int n = blockIdx.x * 256 + threadIdx.x;
    if (n >= N) return;
    if (blockIdx.y == 0) {
        int s0 = off_in[n], s1 = off_in[n + 1];
        float s = 0.0f;
        for (int i = s0; i < s1; ++i) s += (float)(pk_in[i] & 0x7FFFu);
        rdi[n] = 16384.0f / s;     // 1 / deg_in
    } else {
        int s0 = off_out[n], s1 = off_out[n + 1];
        float s = 0.0f;
        for (int i = s0; i < s1; ++i) s += (float)(pk_out[i] & 0x7FFFu);
        rdo[n] = 16384.0f / s;     // 1 / deg_out
    }
}

// wave per (node, direction); lane = channel; bf16 rows (128B = 1 line/row)
__global__ void __launch_bounds__(256) gather_kernel(
        const ushort* __restrict__ hb,
        const int* __restrict__ off_in, const uint* __restrict__ pk_in,
        const float* __restrict__ rdo,
        const int* __restrict__ off_out, const uint* __restrict__ pk_out,
        const float* __restrict__ rdi,
        ushort* __restrict__ pob, ushort* __restrict__ pib, int N) {
    int n = blockIdx.x * 4 + (threadIdx.x >> 6);
    if (n >= N) return;
    int lane = threadIdx.x & 63;

    if (blockIdx.y == 0) {
        // p_o[n] = sum_{col[e]=n} h[row[e]] * rdo[row[e]]
        int s0 = off_in[n], s1 = off_in[n + 1];
        float acc = 0.0f;
        for (int s = s0; s < s1; s += 8) {
            int m = s1 - s;
            int idx[8];
#pragma unroll
            for (int j = 0; j < 8; ++j)
                idx[j] = (int)(pk_in[(s + j < s1) ? s + j : s1 - 1] >> 15);
            float w[8];
#pragma unroll
            for (int j = 0; j < 8; ++j) w[j] = (j < m) ? rdo[idx[j]] : 0.0f;
            float v[8];
#pragma unroll
            for (int j = 0; j < 8; ++j) v[j] = bf2f(hb[(size_t)idx[j] * 64 + lane]);
#pragma unroll
            for (int j = 0; j < 8; ++j) acc = fmaf(v[j], w[j], acc);
        }
        pob[(size_t)n * 64 + lane] = f2bf(acc);
    } else {
        // p_i[n] = rdi[n] * sum_{row[e]=n} h[col[e]]
        int s0 = off_out[n], s1 = off_out[n + 1];
        float acc = 0.0f;
        for (int s = s0; s < s1; s += 8) {
            int m = s1 - s;
            int idx[8];
#pragma unroll
            for (int j = 0; j < 8; ++j)
                idx[j] = (int)(pk_out[(s + j < s1) ? s + j : s1 - 1] >> 15);
            float v[8];
#pragma unroll
            for (int j = 0; j < 8; ++j) v[j] = bf2f(hb[(size_t)idx[j] * 64 + lane]);
#pragma unroll
            for (int j = 0; j < 8; ++j) acc += (j < m) ? v[j] : 0.0f;
        }
        pib[(size_t)n * 64 + lane] = f2bf(acc * rdi[n]);
    }
}

// MFMA gate GEMM + in-register GRU combine + output projection.
__global__ void __launch_bounds__(256) gates_kernel(
        const ushort* __restrict__ hb, const ushort* __restrict__ pob,
        const ushort* __restrict__ pib, const ushort* __restrict__ Wp,
        const float* __restrict__ bc, const float* __restrict__ wout,
        const float* __restrict__ bout, float* __restrict__ out, int N) {
    __shared__ float sS[64 * 68];
    __shared__ float sWO[64 * 12];
    const int t    = threadIdx.x;
    const int w    = t >> 6;
    const int lane = t & 63;
    const int n0   = blockIdx.x * 64;

    for (int i = t; i < 64 * 12; i += 256) sWO[i] = wout[i];

    f32x4 acc[8];
#pragma unroll
    for (int ct = 0; ct < 8; ++ct) {
        float bcv = bc[ct * 16 + (lane & 15)];
        acc[ct] = (f32x4){bcv, bcv, bcv, bcv};
    }

    int arow = n0 + w * 16 + (lane & 15);
    if (arow >= N) arow = N - 1;
    const int g8 = (lane >> 4) * 8;
    const ushort* const srcs[3] = {hb, pob, pib};

#pragma unroll
    for (int kc = 0; kc < 6; ++kc) {
        const ushort* src = srcs[kc >> 1];
        bf16x8 a = *(const bf16x8*)(src + (size_t)arow * 64 + (kc & 1) * 32 + g8);
#pragma unroll
        for (int ct = 0; ct < 8; ++ct) {
            bf16x8 b = *(const bf16x8*)(Wp + (size_t)((kc * 8 + ct) * 64 + lane) * 8);
            acc[ct] = __builtin_amdgcn_mfma_f32_16x16x32_bf16(a, b, acc[ct], 0, 0, 0);
        }
    }

    // GRU combine: z tile ct pairs with h tile ct+4 (same lane/reg)
    const int rowbase = w * 16 + (lane >> 4) * 4;
    const int colbase = lane & 15;
#pragma unroll
    for (int ct = 0; ct < 4; ++ct) {
#pragma unroll
        for (int r = 0; r < 4; ++r) {
            float zv = sigmoid_f(acc[ct][r]);
            float ht = tanh_f(acc[ct + 4][r]);
            sS[(rowbase + r) * 68 + ct * 16 + colbase] =
                sigmoid_f((1.0f - zv) * ht);
        }
    }
    __syncthreads();

    // out[node][j] = s[node] . WO[:,j] + bout[j]
#pragma unroll
    for (int rr = 0; rr < 3; ++rr) {
        int o = rr * 256 + t;
        int node = o / 12;
        int j = o % 12;
        int n = n0 + node;
        if (n >= N) continue;
        float a = bout[j];
#pragma unroll 8
        for (int c2 = 0; c2 < 64; ++c2) a = fmaf(sS[node * 68 + c2], sWO[c2 * 12 + j], a);
        out[(size_t)n * 12 + j] = a;
    }
}

extern "C" void kernel_launch(void* const* d_in, const int* in_sizes, int n_in,
                              void* d_out, int out_size, void* d_ws, size_t ws_size,
                              hipStream_t stream) {
    const float* x      = (const float*)d_in[0];
    const int*   ei     = (const int*)  d_in[1];
    const float* ew     = (const float*)d_in[2];
    const float* w_lin2 = (const float*)d_in[3];
    const float* b_lin2 = (const float*)d_in[4];
    const float* w_z    = (const float*)d_in[5];
    const float* b_z    = (const float*)d_in[6];
    // d_in[7], d_in[8]: w_r, b_r — dead (h0 == 0)
    const float* w_h    = (const float*)d_in[9];
    const float* b_h    = (const float*)d_in[10];
    const float* w_out  = (const float*)d_in[11];
    const float* b_out  = (const float*)d_in[12];

    int N = in_sizes[0] / 24;
    int E = in_sizes[1] / 2;
    const int* row = ei;
    const int* col = ei + E;
    int G = (N + 255) / 256;   // <= 512 required by scan2

    ushort* hb  = (ushort*)d_ws;               // N*64 bf16
    ushort* pob = hb  + (size_t)N * 64;        // N*64 bf16
    ushort* pib = pob + (size_t)N * 64;        // N*64 bf16
    ushort* Wp  = pib + (size_t)N * 64;        // 24576 bf16 (packed frags)
    float*  bc  = (float*)(Wp + 24576);        // 128
    uint* cnt_out = (uint*)(bc + 128);         // N (zeroed)
    uint* cnt_in  = cnt_out + N;               // N (zeroed)
    float* rdo  = (float*)(cnt_in + N);        // N
    float* rdi  = rdo + N;                     // N
    int* off_in  = (int*)(rdi + N);            // N+1
    int* off_out = off_in + N + 1;             // N+1
    int* slot_in  = off_out + N + 1;           // E
    int* slot_out = slot_in + E;               // E
    uint* pk_in  = (uint*)(slot_out + E);      // E  (idx<<15 | fix14(w))
    uint* pk_out = pk_in + E;                  // E
    int* bsum_in  = (int*)(pk_out + E);        // 512
    int* bsum_out = bsum_in + 512;             // 512

    hipMemsetAsync(cnt_out, 0, (size_t)N * 2 * sizeof(uint), stream);

    int EB = (E + 255) / 256;
    int LB = (N * 64 + 255) / 256;
    int PB = (6 * 8 * 64 * 8 + 255) / 256;
    phase1_kernel<<<EB + LB + PB, 256, 0, stream>>>(
        row, col, cnt_out, cnt_in, slot_out, slot_in, E,
        x, w_lin2, b_lin2, hb, N,
        w_z, b_z, w_h, b_h, Wp, bc, EB, LB);
    scan1_kernel<<<dim3(G, 2), 256, 0, stream>>>(cnt_in, off_in, bsum_in,
                                                 cnt_out, off_out, bsum_out, N);
    scan2_kernel<<<dim3(1, 2), 512, 0, stream>>>(bsum_in, off_in, bsum_out, off_out, G, N);
    scan3_kernel<<<dim3(G, 2), 256, 0, stream>>>(off_in, bsum_in, off_out, bsum_out, N);
    fill_kernel<<<(E + 255) / 256, 256, 0, stream>>>(row, col, ew, off_in, off_out,
                                                     slot_in, slot_out, pk_in, pk_out, E);
    deg_kernel<<<dim3(G, 2), 256, 0, stream>>>(off_in, pk_in, rdi,
                                               off_out, pk_out, rdo, N);
    gather_kernel<<<dim3((N + 3) / 4, 2), 256, 0, stream>>>(hb, off_in, pk_in, rdo,
                                                            off_out, pk_out, rdi,
                                                            pob, pib, N);
    gates_kernel<<<(N + 63) / 64, 256, 0, stream>>>(hb, pob, pib, Wp, bc,
                                                    w_out, b_out, (float*)d_out, N);
}